// Round 7
// baseline (1186.481 us; speedup 1.0000x reference)
//
#include <hip/hip_runtime.h>

namespace {

constexpr int E_  = 300;
constexpr int FF_ = 100;
constexpr int AD_ = 64;
constexpr int NH_ = 32;
constexpr int CD_ = 192;   // 3*AD
constexpr int B_  = 16;
constexpr int TQ_ = 32;
constexpr int TD_ = 512;
constexpr int NK_ = 11;
constexpr int DOCBLK_ = 512;   // 8192 doc tokens / 16 per block

__device__ __forceinline__ float wave_sum(float v) {
#pragma unroll
  for (int o = 32; o > 0; o >>= 1) v += __shfl_down(v, o);
  return v;
}

// swizzled transposed activation slot: [e][t], t in 0..15; XOR on bits>=1 so
// even token pairs stay contiguous (b64 reads), banks spread for col reads.
__device__ __forceinline__ int swz16(int e, int t) {
  return e * 16 + (t ^ (((e >> 2) & 7) << 1));
}

__device__ __forceinline__ void fma4(float4& a, float s, const float4& w) {
  a.x = fmaf(s, w.x, a.x); a.y = fmaf(s, w.y, a.y);
  a.z = fmaf(s, w.z, a.z); a.w = fmaf(s, w.w, a.w);
}

// ---------------------------------------------------------------------------
// encode_front_v8: R2's proven v4 structure (16 tok/block, 256 thr, 2 tok per
// thread, LDS-chunked weights) + T14 async-stage split: prefetch chunk c+1
// into registers during compute of chunk c; commit to the single 24 KB LDS
// buffer at the top of the next iteration (barriers drain only LDS writes).
// ---------------------------------------------------------------------------
__global__ __launch_bounds__(256)
void encode_front_v8(const float* __restrict__ qe, const float* __restrict__ de,
                     const float* __restrict__ W1, const float* __restrict__ b1,
                     const float* __restrict__ W2, const float* __restrict__ b2,
                     const float* __restrict__ ffg, const float* __restrict__ ffb,
                     const float* __restrict__ Wc, const float* __restrict__ bc,
                     float* __restrict__ ffq, float* __restrict__ combq,
                     float* __restrict__ qn,
                     float* __restrict__ ffd, float* __restrict__ combd,
                     float* __restrict__ dnT)
{
  __shared__ float  s_A[4800];    // x / ff transposed+swizzled [e][16]
  __shared__ float  s_h1[1600];   // h1 transposed+swizzled     [c][16]
  __shared__ float4 s_w4[1500];   // weight chunk buffer (24 KB, single)
  __shared__ float  s_stat[16][17];
  __shared__ float  s_norm[16];

  const int tid = threadIdx.x;
  const int ct = tid & 31, tg = tid >> 5;
  const int t0 = tg * 2;
  const bool doc = (blockIdx.x < DOCBLK_);
  const int sb = doc ? blockIdx.x : (blockIdx.x - DOCBLK_);
  const float* xs = (doc ? de : qe) + (size_t)sb * 16 * E_;
  float* ffo = doc ? ffd : ffq;
  float* cmo = doc ? combd : combq;
  const size_t tok0 = (size_t)sb * 16;
  const int bb_ = doc ? (int)(tok0 >> 9) : (int)(tok0 >> 5);
  const int tp0 = doc ? (int)(tok0 & 511) : (int)(tok0 & 31);

  const float4* W1f4 = (const float4*)W1;   // 300x100 -> 1500 f4, 5 chunks
  const float4* W2f4 = (const float4*)W2;   // 100x300 -> 7500 f4, 5 chunks
  const float4* Wcf4 = (const float4*)Wc;   // 300x192 -> 14400 f4, 10 chunks

  float4 r0, r1, r2, r3, r4, r5;
#define LOADC(srcp, n) { const float4* _s = (srcp); \
    r0 = _s[tid]; r1 = _s[tid + 256]; r2 = _s[tid + 512]; \
    r3 = _s[tid + 768]; r4 = _s[tid + 1024]; \
    if (tid + 1280 < (n)) r5 = _s[tid + 1280]; }
#define COMMITC(n) { s_w4[tid] = r0; s_w4[tid + 256] = r1; s_w4[tid + 512] = r2; \
    s_w4[tid + 768] = r3; s_w4[tid + 1024] = r4; \
    if (tid + 1280 < (n)) s_w4[tid + 1280] = r5; }

  // prefetch chunk 0 (W1 part 0) — lands while we do init/posenc
  LOADC(W1f4, 1500);

  // ---- init: raw x -> s_A ----
  for (int i = tid; i < 1200; i += 256) {
    const float4 v = *(const float4*)(xs + (size_t)i * 4);
    const int t = i / 75, e0 = (i % 75) * 4;
    s_A[swz16(e0 + 0, t)] = v.x; s_A[swz16(e0 + 1, t)] = v.y;
    s_A[swz16(e0 + 2, t)] = v.z; s_A[swz16(e0 + 3, t)] = v.w;
  }
  __syncthreads();
  { // per-token sumsq of raw x (for xn)
    const int tk = tid & 15, ch = tid >> 4;
    const int kb = ch * 19, ke = (kb + 19 < 300) ? kb + 19 : 300;
    float ss = 0.f;
    for (int k = kb; k < ke; ++k) { const float v = s_A[swz16(k, tk)]; ss = fmaf(v, v, ss); }
    s_stat[ch][tk] = ss;
  }
  __syncthreads();
  if (tid < 16) {
    float s = 0.f;
#pragma unroll
    for (int i = 0; i < 16; ++i) s += s_stat[i][tid];
    s_norm[tid] = 1.f / (sqrtf(s) + 1e-13f);
  }
  __syncthreads();
  // ---- xn write + posenc add (in place) ----
  for (int i = tid; i < 1200; i += 256) {
    const int t = i / 75, e0 = (i % 75) * 4;
    const int tp = tp0 + t;
    const float nm = s_norm[t];
#pragma unroll
    for (int j = 0; j < 4; ++j) {
      const int e = e0 + j;
      const int slot = swz16(e, t);
      const float raw = s_A[slot];
      if (doc) dnT[((size_t)bb_ * E_ + e) * 512 + tp] = raw * nm;
      else     qn[(tok0 + t) * E_ + e] = raw * nm;
      const int f = (e < 150) ? e : e - 150;
      const float ang = __expf(-0.061814365f * (float)f) * (float)tp;
      s_A[slot] = raw + ((e < 150) ? sinf(ang) : cosf(ang));
    }
  }
  __syncthreads();   // s_A(posenc) ready

  // ---- phase 1: h1 = relu(out @ W1 + b1), chunks 0..4 (60 rows each) ----
  {
    const int cq = (ct < 25) ? ct : 24;
    float4 a1[2];
    a1[0] = make_float4(0.f, 0.f, 0.f, 0.f);
    a1[1] = make_float4(0.f, 0.f, 0.f, 0.f);
    for (int c = 0; c < 5; ++c) {
      COMMITC(1500);
      __syncthreads();
      if (c < 4) LOADC(W1f4 + 1500 * (c + 1), 1500)
      else       LOADC(W2f4, 1500)
#pragma unroll 6
      for (int kk = 0; kk < 60; ++kk) {
        const float2 xv = *(const float2*)&s_A[swz16(c * 60 + kk, t0)];
        const float4 w = s_w4[kk * 25 + cq];
        fma4(a1[0], xv.x, w); fma4(a1[1], xv.y, w);
      }
      if (c == 4 && ct < 25) {
        const float4 bb = *(const float4*)&b1[4 * ct];
#pragma unroll
        for (int rr = 0; rr < 2; ++rr) {
          const int t = t0 + rr;
          const float4 a = (rr == 0) ? a1[0] : a1[1];
          s_h1[swz16(4 * ct + 0, t)] = fmaxf(a.x + bb.x, 0.f);
          s_h1[swz16(4 * ct + 1, t)] = fmaxf(a.y + bb.y, 0.f);
          s_h1[swz16(4 * ct + 2, t)] = fmaxf(a.z + bb.z, 0.f);
          s_h1[swz16(4 * ct + 3, t)] = fmaxf(a.w + bb.w, 0.f);
        }
      }
      __syncthreads();
    }
  }

  // ---- phase 2: ff0 = h1 @ W2 + b2 + out; LN -> ff. chunks 5..9 (20 rows) --
  {
    const int q2 = (ct < 11) ? ct + 64 : 74;
    const bool val2 = (ct < 11);
    float4 a2[3][2];
#pragma unroll
    for (int p = 0; p < 3; ++p)
#pragma unroll
      for (int rr = 0; rr < 2; ++rr) a2[p][rr] = make_float4(0.f, 0.f, 0.f, 0.f);
    for (int c = 0; c < 5; ++c) {
      COMMITC(1500);
      __syncthreads();
      if (c < 4) LOADC(W2f4 + 1500 * (c + 1), 1500)
      else       LOADC(Wcf4, 1440)
#pragma unroll 5
      for (int kk = 0; kk < 20; ++kk) {
        const float2 hv = *(const float2*)&s_h1[swz16(c * 20 + kk, t0)];
        const float4 w0 = s_w4[kk * 75 + ct];
        const float4 w1 = s_w4[kk * 75 + ct + 32];
        const float4 w2 = s_w4[kk * 75 + q2];
        fma4(a2[0][0], hv.x, w0); fma4(a2[0][1], hv.y, w0);
        fma4(a2[1][0], hv.x, w1); fma4(a2[1][1], hv.y, w1);
        fma4(a2[2][0], hv.x, w2); fma4(a2[2][1], hv.y, w2);
      }
      if (c == 4) {
        // epilogue: bias + residual + LN stats + ff write (same-thread slots)
        float sum[2] = {0.f, 0.f}, sq[2] = {0.f, 0.f};
#pragma unroll
        for (int p = 0; p < 3; ++p) {
          const int qq = (p == 0) ? ct : (p == 1) ? ct + 32 : q2;
          const bool ok = (p < 2) || val2;
          if (!ok) break;
          const float4 bb = *(const float4*)&b2[4 * qq];
#pragma unroll
          for (int rr = 0; rr < 2; ++rr) {
            const int t = t0 + rr;
            float4 v = a2[p][rr];
            v.x += bb.x + s_A[swz16(4 * qq + 0, t)];
            v.y += bb.y + s_A[swz16(4 * qq + 1, t)];
            v.z += bb.z + s_A[swz16(4 * qq + 2, t)];
            v.w += bb.w + s_A[swz16(4 * qq + 3, t)];
            a2[p][rr] = v;
            sum[rr] += v.x + v.y + v.z + v.w;
            sq[rr] = fmaf(v.x, v.x, fmaf(v.y, v.y, fmaf(v.z, v.z, fmaf(v.w, v.w, sq[rr]))));
          }
        }
#pragma unroll
        for (int m = 1; m <= 16; m <<= 1) {
#pragma unroll
          for (int rr = 0; rr < 2; ++rr) {
            sum[rr] += __shfl_xor(sum[rr], m);
            sq[rr]  += __shfl_xor(sq[rr], m);
          }
        }
#pragma unroll
        for (int rr = 0; rr < 2; ++rr) {
          const int t = t0 + rr;
          const float mean = sum[rr] * (1.f / 300.f);
          const float var  = fmaxf(sq[rr] * (1.f / 300.f) - mean * mean, 0.f);
          const float rstd = 1.f / (sqrtf(var) + 1e-6f);
#pragma unroll
          for (int p = 0; p < 3; ++p) {
            if (p == 2 && !val2) break;
            const int qq = (p == 0) ? ct : (p == 1) ? ct + 32 : q2;
            const int c0 = 4 * qq;
            const float4 g4 = *(const float4*)&ffg[c0];
            const float4 b4 = *(const float4*)&ffb[c0];
            const float4 v = a2[p][rr];
            float4 fv;
            fv.x = fmaf(g4.x, (v.x - mean) * rstd, b4.x);
            fv.y = fmaf(g4.y, (v.y - mean) * rstd, b4.y);
            fv.z = fmaf(g4.z, (v.z - mean) * rstd, b4.z);
            fv.w = fmaf(g4.w, (v.w - mean) * rstd, b4.w);
            *(float4*)&ffo[(tok0 + t) * E_ + c0] = fv;
            s_A[swz16(c0 + 0, t)] = fv.x; s_A[swz16(c0 + 1, t)] = fv.y;
            s_A[swz16(c0 + 2, t)] = fv.z; s_A[swz16(c0 + 3, t)] = fv.w;
          }
        }
      }
      __syncthreads();
    }
  }

  // ---- phase 3: comb = ff @ Wc + bc. chunks 10..19 (30 rows each) ----
  {
    const int q3 = (ct < 16) ? ct + 32 : 47;
    float4 a3[2][2];
#pragma unroll
    for (int p = 0; p < 2; ++p)
#pragma unroll
      for (int rr = 0; rr < 2; ++rr) a3[p][rr] = make_float4(0.f, 0.f, 0.f, 0.f);
    for (int c = 0; c < 10; ++c) {
      COMMITC(1440);
      __syncthreads();
      if (c < 9) LOADC(Wcf4 + 1440 * (c + 1), 1440)
#pragma unroll 6
      for (int kk = 0; kk < 30; ++kk) {
        const float2 xv = *(const float2*)&s_A[swz16(c * 30 + kk, t0)];
        const float4 w0 = s_w4[kk * 48 + ct];
        const float4 w1 = s_w4[kk * 48 + q3];
        fma4(a3[0][0], xv.x, w0); fma4(a3[0][1], xv.y, w0);
        fma4(a3[1][0], xv.x, w1); fma4(a3[1][1], xv.y, w1);
      }
      if (c < 9) __syncthreads();
    }
    const float4 bb0 = *(const float4*)&bc[4 * ct];
#pragma unroll
    for (int rr = 0; rr < 2; ++rr) {
      float4 o = a3[0][rr];
      o.x += bb0.x; o.y += bb0.y; o.z += bb0.z; o.w += bb0.w;
      *(float4*)&cmo[(tok0 + t0 + rr) * CD_ + 4 * ct] = o;
    }
    if (ct < 16) {
      const float4 bb1 = *(const float4*)&bc[4 * (ct + 32)];
#pragma unroll
      for (int rr = 0; rr < 2; ++rr) {
        float4 o = a3[1][rr];
        o.x += bb1.x; o.y += bb1.y; o.z += bb1.z; o.w += bb1.w;
        *(float4*)&cmo[(tok0 + t0 + rr) * CD_ + 4 * (ct + 32)] = o;
      }
    }
  }
#undef LOADC
#undef COMMITC
}

// ---------------------------------------------------------------------------
// attention: one block per (b,h); thread = query pos. Two-pass softmax.
// ---------------------------------------------------------------------------
template <int T>
__global__ __launch_bounds__(512)
void attn(const float* __restrict__ comb, const float* __restrict__ mask,
          float* __restrict__ o)
{
  __shared__ float4 s_kv[T];  // (k0*m, k1*m, v0, v1)
  __shared__ float  s_m[T];
  const int bh = blockIdx.x, b = bh / NH_, h = bh % NH_;
  const int tid = threadIdx.x;
  const float* cb = comb + (size_t)b * T * CD_;
  if (tid < T) {
    const float* c = cb + (size_t)tid * CD_;
    const float m = mask[b * T + tid];
    s_kv[tid] = make_float4(c[AD_ + 2 * h] * m, c[AD_ + 2 * h + 1] * m,
                            c[2 * AD_ + 2 * h], c[2 * AD_ + 2 * h + 1]);
    s_m[tid] = m;
  }
  __syncthreads();
  if (tid < T) {
    const float* c = cb + (size_t)tid * CD_;
    const float q0 = c[2 * h] * (1.f / 3.f);
    const float q1 = c[2 * h + 1] * (1.f / 3.f);
    float M = -1e30f;
    for (int j = 0; j < T; ++j) {
      const float4 kv = s_kv[j];
      M = fmaxf(M, fmaf(q0, kv.x, q1 * kv.y));
    }
    float S = 0.f, W = 0.f, a0 = 0.f, a1 = 0.f;
    for (int j = 0; j < T; ++j) {
      const float4 kv = s_kv[j];
      const float s = fmaf(q0, kv.x, q1 * kv.y);
      const float z = __expf(s - M);
      const float w = z * s_m[j];
      S += z; W += w;
      a0 = fmaf(w, kv.z, a0);
      a1 = fmaf(w, kv.w, a1);
    }
    const float dn = 1.f / (W + 1e-13f * S);
    float* op = o + (size_t)(b * T + tid) * AD_ + 2 * h;
    op[0] = a0 * dn;
    op[1] = a1 * dn;
  }
}

// ---------------------------------------------------------------------------
// encode_back_v8: merged doc+query, 16 tokens/block, Wo chunked via single
// 19.2 KB LDS buffer + T14 register prefetch (4 chunks of 16 rows).
// ---------------------------------------------------------------------------
__global__ __launch_bounds__(256)
void encode_back_v8(const float* __restrict__ oq, const float* __restrict__ od,
                    const float* __restrict__ ffq, const float* __restrict__ ffd,
                    const float* __restrict__ Wo, const float* __restrict__ bo,
                    const float* __restrict__ lng, const float* __restrict__ lnb,
                    const float* __restrict__ qm, const float* __restrict__ dm,
                    float* __restrict__ qctx, float* __restrict__ dctxT)
{
  __shared__ float  s_O[1024];     // o transposed+swizzled [c][16]
  __shared__ float4 s_wb[1200];    // Wo chunk buffer (19.2 KB, single)

  const int tid = threadIdx.x;
  const int ct = tid & 31, tg = tid >> 5;
  const int t0 = tg * 2;
  const bool doc = (blockIdx.x < DOCBLK_);
  const int sb = doc ? blockIdx.x : (blockIdx.x - DOCBLK_);
  const size_t tok0 = (size_t)sb * 16;
  const float* op = doc ? od : oq;
  const float* ffp = doc ? ffd : ffq;
  const float* mp = doc ? dm : qm;
  const int bb_ = doc ? (int)(tok0 >> 9) : 0;
  const int tp0 = doc ? (int)(tok0 & 511) : 0;

  const float4* Wof4 = (const float4*)Wo;   // 64x300 -> 4800 f4, 4 chunks x 1200

  float4 r0, r1, r2, r3, r4;
#define LOADB(srcp) { const float4* _s = (srcp); \
    r0 = _s[tid]; r1 = _s[tid + 256]; r2 = _s[tid + 512]; r3 = _s[tid + 768]; \
    if (tid + 1024 < 1200) r4 = _s[tid + 1024]; }
#define COMMITB() { s_wb[tid] = r0; s_wb[tid + 256] = r1; s_wb[tid + 512] = r2; \
    s_wb[tid + 768] = r3; if (tid + 1024 < 1200) s_wb[tid + 1024] = r4; }

  LOADB(Wof4);

  { // load o (16x64) transposed into s_O
    const int t = tid >> 4, c0 = (tid & 15) * 4;
    const float4 v = *(const float4*)(op + (tok0 + t) * AD_ + c0);
    s_O[swz16(c0 + 0, t)] = v.x; s_O[swz16(c0 + 1, t)] = v.y;
    s_O[swz16(c0 + 2, t)] = v.z; s_O[swz16(c0 + 3, t)] = v.w;
  }
  __syncthreads();

  const int q2 = (ct < 11) ? ct + 64 : 74;
  const bool val2 = (ct < 11);
  float4 a[3][2];
#pragma unroll
  for (int p = 0; p < 3; ++p)
#pragma unroll
    for (int rr = 0; rr < 2; ++rr) a[p][rr] = make_float4(0.f, 0.f, 0.f, 0.f);
  for (int c = 0; c < 4; ++c) {
    COMMITB();
    __syncthreads();
    if (c < 3) LOADB(Wof4 + 1200 * (c + 1))
#pragma unroll 4
    for (int kk = 0; kk < 16; ++kk) {
      const float2 ov = *(const float2*)&s_O[swz16(c * 16 + kk, t0)];
      const float4 w0 = s_wb[kk * 75 + ct];
      const float4 w1 = s_wb[kk * 75 + ct + 32];
      const float4 w2 = s_wb[kk * 75 + q2];
      fma4(a[0][0], ov.x, w0); fma4(a[0][1], ov.y, w0);
      fma4(a[1][0], ov.x, w1); fma4(a[1][1], ov.y, w1);
      fma4(a[2][0], ov.x, w2); fma4(a[2][1], ov.y, w2);
    }
    if (c < 3) __syncthreads();
  }
  // residual + LN stats
  float sum[2] = {0.f, 0.f}, sq[2] = {0.f, 0.f};
#pragma unroll
  for (int p = 0; p < 3; ++p) {
    const int qq = (p == 0) ? ct : (p == 1) ? ct + 32 : q2;
    const bool ok = (p < 2) || val2;
    if (!ok) break;
    const float4 bb = *(const float4*)&bo[4 * qq];
#pragma unroll
    for (int rr = 0; rr < 2; ++rr) {
      const int t = t0 + rr;
      const float4 f4 = *(const float4*)(ffp + (tok0 + t) * E_ + 4 * qq);
      float4 v = a[p][rr];
      v.x += bb.x + f4.x; v.y += bb.y + f4.y;
      v.z += bb.z + f4.z; v.w += bb.w + f4.w;
      a[p][rr] = v;
      sum[rr] += v.x + v.y + v.z + v.w;
      sq[rr] = fmaf(v.x, v.x, fmaf(v.y, v.y, fmaf(v.z, v.z, fmaf(v.w, v.w, sq[rr]))));
    }
  }
#pragma unroll
  for (int m = 1; m <= 16; m <<= 1) {
#pragma unroll
    for (int rr = 0; rr < 2; ++rr) {
      sum[rr] += __shfl_xor(sum[rr], m);
      sq[rr]  += __shfl_xor(sq[rr], m);
    }
  }
#pragma unroll
  for (int rr = 0; rr < 2; ++rr) {
    const int t = t0 + rr;
    const float mean = sum[rr] * (1.f / 300.f);
    const float var  = fmaxf(sq[rr] * (1.f / 300.f) - mean * mean, 0.f);
    const float rstd = 1.f / (sqrtf(var) + 1e-6f);
    const float mk = mp[tok0 + t];
#pragma unroll
    for (int p = 0; p < 3; ++p) {
      if (p == 2 && !val2) break;
      const int qq = (p == 0) ? ct : (p == 1) ? ct + 32 : q2;
      const int c0 = 4 * qq;
      const float4 g4 = *(const float4*)&lng[c0];
      const float4 b4 = *(const float4*)&lnb[c0];
      const float4 v = a[p][rr];
      float4 fv;
      fv.x = fmaf(g4.x, (v.x - mean) * rstd, b4.x) * mk;
      fv.y = fmaf(g4.y, (v.y - mean) * rstd, b4.y) * mk;
      fv.z = fmaf(g4.z, (v.z - mean) * rstd, b4.z) * mk;
      fv.w = fmaf(g4.w, (v.w - mean) * rstd, b4.w) * mk;
      if (doc) {
        const int tp = tp0 + t;
        dctxT[((size_t)bb_ * E_ + c0 + 0) * 512 + tp] = fv.x;
        dctxT[((size_t)bb_ * E_ + c0 + 1) * 512 + tp] = fv.y;
        dctxT[((size_t)bb_ * E_ + c0 + 2) * 512 + tp] = fv.z;
        dctxT[((size_t)bb_ * E_ + c0 + 3) * 512 + tp] = fv.w;
      } else {
        *(float4*)&qctx[(tok0 + t) * E_ + c0] = fv;
      }
    }
  }
#undef LOADB
#undef COMMITB
}

// ---------------------------------------------------------------------------
// simtanh_v2: 256 blocks (b,qh,dc: 16x2x8) x 512 threads (epart=wave 0..7,
// dlane 0..63). Partial dots + LDS reduce, tanh, coalesced store.
// ---------------------------------------------------------------------------
__global__ __launch_bounds__(512)
void simtanh_v2(const float* __restrict__ qctx, const float* __restrict__ qn,
                const float* __restrict__ dctxT, const float* __restrict__ dnT,
                float* __restrict__ combined)
{
  __shared__ float s_q[2 * 16 * 304];     // [type][q][e]
  __shared__ float s_part[8 * 32 * 64];   // [epart][q*2+type][dlane]

  const int bid = blockIdx.x;
  const int sub = bid & 15, b = bid >> 4;
  const int qh = sub >> 3, dc = sub & 7;
  const int tid = threadIdx.x;
  const int ep = tid >> 6, dlane = tid & 63;
  const int d = dc * 64 + dlane;

  const float* qc  = qctx + ((size_t)b * 32 + qh * 16) * E_;
  const float* qnp = qn   + ((size_t)b * 32 + qh * 16) * E_;
  for (int i = tid; i < 1200; i += 512) {
    const int q = i / 75, e0 = (i % 75) * 4;
    *(float4*)&s_q[(0 * 16 + q) * 304 + e0] = *(const float4*)(qc + q * E_ + e0);
    *(float4*)&s_q[(1 * 16 + q) * 304 + e0] = *(const float4*)(qnp + q * E_ + e0);
  }
  __syncthreads();

  const float* dct = dctxT + (size_t)b * E_ * 512 + d;
  const float* dnt = dnT   + (size_t)b * E_ * 512 + d;
  float accD[16], accC[16];
#pragma unroll
  for (int q = 0; q < 16; ++q) { accD[q] = 0.f; accC[q] = 0.f; }
  const int es = ep * 40, ee = (es + 40 < 300) ? es + 40 : 300;
  for (int e0 = es; e0 < ee; e0 += 4) {
    const float dv0 = dct[(size_t)(e0 + 0) * 512];
    const float dv1 = dct[(size_t)(e0 + 1) * 512];
    const float dv2 = dct[(size_t)(e0 + 2) * 512];
    const float dv3 = dct[(size_t)(e0 + 3) * 512];
    const float dn0 = dnt[(size_t)(e0 + 0) * 512];
    const float dn1 = dnt[(size_t)(e0 + 1) * 512];
    const float dn2 = dnt[(size_t)(e0 + 2) * 512];
    const float dn3 = dnt[(size_t)(e0 + 3) * 512];
#pragma unroll
    for (int q = 0; q < 16; ++q) {
      const float4 qd = *(const float4*)&s_q[(0 * 16 + q) * 304 + e0];
      const float4 qc4 = *(const float4*)&s_q[(1 * 16 + q) * 304 + e0];
      float aD = accD[q], aC = accC[q];
      aD = fmaf(qd.x, dv0, aD); aD = fmaf(qd.y, dv1, aD);
      aD = fmaf(qd.z, dv2, aD); aD = fmaf(qd.w, dv3, aD);
      aC = fmaf(qc4.x, dn0, aC); aC = fmaf(qc4.y, dn1, aC);
      aC = fmaf(qc4.z, dn2, aC); aC = fmaf(qc4.w, dn3, aC);
      accD[q] = aD; accC[q] = aC;
    }
  }
#pragma unroll
  for (int q = 0; q < 16; ++q) {
    s_part[(ep * 32 + q * 2 + 0) * 64 + dlane] = accC[q];  // cos
    s_part[(ep * 32 + q * 2 + 1) * 64 + dlane] = accD[q];  // dot
  }
  __syncthreads();
  const int s0 = (tid >> 6) * 4;
#pragma unroll
  for (int si = 0; si < 4; ++si) {
    const int s = s0 + si;
    float v = 0.f;
#pragma unroll
    for (int p = 0; p < 8; ++p) v += s_part[(p * 32 + s) * 64 + dlane];
    const int q = s >> 1, typ = s & 1;
    combined[(((size_t)b * 2 + typ) * 32 + qh * 16 + q) * 512 + d] = tanhf(v);
  }
}

// ---------------------------------------------------------------------------
// conv_rbf: 5 convs (k=1..5, end-padded) + channel-max, FUSED with the RBF
// kernel-pooling sum over d. Block (b, q-row i) x 512 j-threads; in-block
// reduce produces pkq[b][c][q][k] directly (convout buffer eliminated).
// ---------------------------------------------------------------------------
template <int K>
__device__ __forceinline__ float conv_max16(const float* __restrict__ s_in, int j,
                                            const float* __restrict__ w,
                                            const float* __restrict__ bias)
{
  float patch[2][K][K];
#pragma unroll
  for (int c = 0; c < 2; ++c)
#pragma unroll
    for (int di = 0; di < K; ++di)
#pragma unroll
      for (int dj = 0; dj < K; ++dj)
        patch[c][di][dj] = s_in[(c * 5 + di) * 516 + j + dj];
  float best = -1e30f;
#pragma unroll
  for (int oc = 0; oc < 16; ++oc) {
    float acc = bias[oc];
#pragma unroll
    for (int c = 0; c < 2; ++c)
#pragma unroll
      for (int di = 0; di < K; ++di)
#pragma unroll
        for (int dj = 0; dj < K; ++dj)
          acc = fmaf(patch[c][di][dj], w[((oc * 2 + c) * K + di) * K + dj], acc);
    best = fmaxf(best, acc);
  }
  return best;
}

__global__ __launch_bounds__(512)
void conv_rbf(const float* __restrict__ combined,
              const float* __restrict__ c1w, const float* __restrict__ c1b,
              const float* __restrict__ c2w, const float* __restrict__ c2b,
              const float* __restrict__ c3w, const float* __restrict__ c3b,
              const float* __restrict__ c4w, const float* __restrict__ c4b,
              const float* __restrict__ c5w, const float* __restrict__ c5b,
              const float* __restrict__ dmask, const float* __restrict__ qmask,
              float* __restrict__ pkq)
{
  __shared__ float s_in[2 * 5 * 516];
  __shared__ float s_w[1730];
  __shared__ float s_b[66];
  __shared__ float s_red[8][56];
  const int blk = blockIdx.x, b = blk >> 5, i = blk & 31;
  const int tid = threadIdx.x;
  for (int idx = tid; idx < 2 * 5 * 516; idx += 512) {
    const int c = idx / (5 * 516), rem = idx % (5 * 516), r = rem / 516, j = rem % 516;
    const int row = i + r;
    float v = 0.f;
    if (row < 32 && j < 512)
      v = combined[((size_t)(b * 2 + c) * 32 + row) * 512 + j];
    s_in[idx] = v;
  }
  if (tid < 2)   s_w[tid] = c1w[tid];
  if (tid < 128) s_w[2 + tid] = c2w[tid];
  if (tid < 288) s_w[130 + tid] = c3w[tid];
  s_w[418 + tid] = c4w[tid];
  for (int idx = tid; idx < 800; idx += 512) s_w[930 + idx] = c5w[idx];
  if (tid == 0) s_b[0] = c1b[0];
  if (tid < 16) {
    s_b[1 + tid]  = c2b[tid];
    s_b[17 + tid] = c3b[tid];
    s_b[33 + tid] = c4b[tid];
    s_b[49 + tid] = c5b[tid];
  }
  __syncthreads();
  const int j = tid;
  float val[5];
  val[0] = fmaf(s_in[j], s_w[0], fmaf(s_in[5 * 516 + j], s_w[1], s_b[0]));
  val[1] = conv_max16<2>(s_in, j, s_w + 2,   s_b + 1);
  val[2] = conv_max16<3>(s_in, j, s_w + 130, s_b + 17);
  val[3] = conv_max16<4>(s_in, j, s_w + 418, s_b + 33);
  val[4] = conv_max16<5>(s_in, j, s_w + 930, s_b + 49);

  const float dmv = dmask[b * 512 + j];
  const float mu[NK_]  = {1.f, .9f, .7f, .5f, .3f, .1f, -.1f, -.3f, -.5f, -.7f, -.9f};
  const float nis[NK_] = {-5e7f, -50.f, -50.f, -50.f, -50.f, -50.f,
                          -50.f, -50.f, -50.f, -50.f, -50.f};
  const int lane = tid & 63, w = tid >> 6;
#pragma unroll
  for (int c = 0; c < 5; ++c) {
#pragma unroll
    for (int k = 0; k < NK_; ++k) {
      const float df = val[c] - mu[k];
      float v = __expf(df * df * nis[k]) * dmv;
      v = wave_sum(v);
      if (lane == 0) s_red[w][c * NK_ + k] = v;
    }
  }
  __syncthreads();
  if (tid < 55) {
    float s = 0.f;
#pragma unroll
    for (int ww = 0; ww < 8; ++ww) s += s_red[ww][tid];
    const int c = tid / NK_, k = tid % NK_;
    pkq[((size_t)(b * 5 + c) * 32 + i) * NK_ + k] = s * qmask[b * 32 + i];
  }
}

// ---------------------------------------------------------------------------
// final_k
// ---------------------------------------------------------------------------
__global__ __launch_bounds__(64)
void final_k(const float* __restrict__ pkq, const float* __restrict__ qmask,
             const float* __restrict__ dmask,
             const float* __restrict__ dw, const float* __restrict__ db,
             const float* __restrict__ dmw, const float* __restrict__ dmb,
             const float* __restrict__ cw, float* __restrict__ out)
{
  const int b = blockIdx.x, tid = threadIdx.x;
  float dl = 0.f;
  for (int j = tid; j < 512; j += 64) dl += dmask[b * 512 + j];
  dl = wave_sum(dl);
  dl = __shfl(dl, 0);
  float v1 = 0.f, v2 = 0.f;
  if (tid < 55) {
    const int c = tid / NK_, k = tid % NK_;
    const float rdl = 1.f / dl;
    float s1 = 0.f, s2 = 0.f;
    for (int q = 0; q < 32; ++q) {
      const float p = pkq[(size_t)((b * 5 + c) * 32 + q) * NK_ + k];
      const float qmv = qmask[b * 32 + q];
      s1 += logf(fmaxf(p, 1e-10f)) * qmv;
      s2 += logf(fmaxf(p * rdl, 1e-10f)) * qmv;
    }
    v1 = s1 * dw[tid];
    v2 = s2 * dmw[tid];
  }
  v1 = wave_sum(v1);
  v2 = wave_sum(v2);
  if (tid == 0) out[b] = (v1 + db[0]) * cw[0] + (v2 + dmb[0]) * cw[1];
}

}  // namespace

extern "C" void kernel_launch(void* const* d_in, const int* in_sizes, int n_in,
                              void* d_out, int out_size, void* d_ws, size_t ws_size,
                              hipStream_t stream)
{
  const float* qe  = (const float*)d_in[0];
  const float* de  = (const float*)d_in[1];
  const float* qm  = (const float*)d_in[2];
  const float* dm  = (const float*)d_in[3];
  const float* W1  = (const float*)d_in[6];
  const float* b1  = (const float*)d_in[7];
  const float* W2  = (const float*)d_in[8];
  const float* b2  = (const float*)d_in[9];
  const float* ffg = (const float*)d_in[10];
  const float* ffb = (const float*)d_in[11];
  const float* Wc  = (const float*)d_in[12];
  const float* bc  = (const float*)d_in[13];
  const float* Wo  = (const float*)d_in[14];
  const float* bo  = (const float*)d_in[15];
  const float* lng = (const float*)d_in[16];
  const float* lnb = (const float*)d_in[17];
  const float* c1w = (const float*)d_in[18];
  const float* c1b = (const float*)d_in[19];
  const float* c2w = (const float*)d_in[20];
  const float* c2b = (const float*)d_in[21];
  const float* c3w = (const float*)d_in[22];
  const float* c3b = (const float*)d_in[23];
  const float* c4w = (const float*)d_in[24];
  const float* c4b = (const float*)d_in[25];
  const float* c5w = (const float*)d_in[26];
  const float* c5b = (const float*)d_in[27];
  const float* dwp  = (const float*)d_in[28];
  const float* dbp  = (const float*)d_in[29];
  const float* dmwp = (const float*)d_in[30];
  const float* dmbp = (const float*)d_in[31];
  const float* cwp  = (const float*)d_in[32];

  float* ws = (float*)d_ws;
  size_t off = 0;
  auto alloc = [&](size_t n) { float* p = ws + off; off += n; return p; };
  float* ffq      = alloc((size_t)B_ * TQ_ * E_);
  float* combq    = alloc((size_t)B_ * TQ_ * CD_);
  float* oq       = alloc((size_t)B_ * TQ_ * AD_);
  float* qctx     = alloc((size_t)B_ * TQ_ * E_);
  float* qn       = alloc((size_t)B_ * TQ_ * E_);
  float* ffd      = alloc((size_t)B_ * TD_ * E_);
  float* combd    = alloc((size_t)B_ * TD_ * CD_);
  float* od       = alloc((size_t)B_ * TD_ * AD_);
  float* dctxT    = alloc((size_t)B_ * E_ * TD_);
  float* dnT      = alloc((size_t)B_ * E_ * TD_);
  float* combined = alloc((size_t)B_ * 2 * TQ_ * TD_);
  float* pkq      = alloc((size_t)B_ * 5 * TQ_ * NK_);

  encode_front_v8<<<DOCBLK_ + 32, 256, 0, stream>>>(
      qe, de, W1, b1, W2, b2, ffg, ffb, Wc, bc,
      ffq, combq, qn, ffd, combd, dnT);
  attn<TQ_><<<B_ * NH_, 64, 0, stream>>>(combq, qm, oq);
  attn<TD_><<<B_ * NH_, 512, 0, stream>>>(combd, dm, od);
  encode_back_v8<<<DOCBLK_ + 32, 256, 0, stream>>>(
      oq, od, ffq, ffd, Wo, bo, lng, lnb, qm, dm, qctx, dctxT);
  simtanh_v2<<<256, 512, 0, stream>>>(qctx, qn, dctxT, dnT, combined);
  conv_rbf<<<B_ * 32, 512, 0, stream>>>(
      combined, c1w, c1b, c2w, c2b, c3w, c3b, c4w, c4b, c5w, c5b,
      dm, qm, pkq);
  final_k<<<B_, 64, 0, stream>>>(pkq, qm, dm, dwp, dbp, dmwp, dmbp, cwp,
                                 (float*)d_out);
}

// Round 8
// 366.293 us; speedup vs baseline: 3.2392x; 3.2392x over previous
//
#include <hip/hip_runtime.h>

namespace {

constexpr int E_  = 300;
constexpr int FF_ = 100;
constexpr int AD_ = 64;
constexpr int NH_ = 32;
constexpr int CD_ = 192;   // 3*AD
constexpr int B_  = 16;
constexpr int TQ_ = 32;
constexpr int TD_ = 512;
constexpr int NK_ = 11;
constexpr int DOCBLK_ = 512;   // 8192 doc tokens / 16 per block

__device__ __forceinline__ float wave_sum(float v) {
#pragma unroll
  for (int o = 32; o > 0; o >>= 1) v += __shfl_down(v, o);
  return v;
}

// swizzled transposed activation slot: [e][t], t in 0..15; XOR on bits>=1 so
// even token pairs stay contiguous (b64 reads), banks spread for col reads.
__device__ __forceinline__ int swz16(int e, int t) {
  return e * 16 + (t ^ (((e >> 2) & 7) << 1));
}

__device__ __forceinline__ void fma4(float4& a, float s, const float4& w) {
  a.x = fmaf(s, w.x, a.x); a.y = fmaf(s, w.y, a.y);
  a.z = fmaf(s, w.z, a.z); a.w = fmaf(s, w.w, a.w);
}

// ---------------------------------------------------------------------------
// encode_front_v8: 16 tok/block, 256 thr, 2 tok per thread, LDS-chunked
// weights + T14 async-stage split (prefetch chunk c+1 into registers during
// compute of chunk c; commit to single 24 KB LDS buffer next iteration).
// ---------------------------------------------------------------------------
__global__ __launch_bounds__(256)
void encode_front_v8(const float* __restrict__ qe, const float* __restrict__ de,
                     const float* __restrict__ W1, const float* __restrict__ b1,
                     const float* __restrict__ W2, const float* __restrict__ b2,
                     const float* __restrict__ ffg, const float* __restrict__ ffb,
                     const float* __restrict__ Wc, const float* __restrict__ bc,
                     float* __restrict__ ffq, float* __restrict__ combq,
                     float* __restrict__ qn,
                     float* __restrict__ ffd, float* __restrict__ combd,
                     float* __restrict__ dnT)
{
  __shared__ float  s_A[4800];    // x / ff transposed+swizzled [e][16]
  __shared__ float  s_h1[1600];   // h1 transposed+swizzled     [c][16]
  __shared__ float4 s_w4[1500];   // weight chunk buffer (24 KB, single)
  __shared__ float  s_stat[16][17];
  __shared__ float  s_norm[16];

  const int tid = threadIdx.x;
  const int ct = tid & 31, tg = tid >> 5;
  const int t0 = tg * 2;
  const bool doc = (blockIdx.x < DOCBLK_);
  const int sb = doc ? blockIdx.x : (blockIdx.x - DOCBLK_);
  const float* xs = (doc ? de : qe) + (size_t)sb * 16 * E_;
  float* ffo = doc ? ffd : ffq;
  float* cmo = doc ? combd : combq;
  const size_t tok0 = (size_t)sb * 16;
  const int bb_ = doc ? (int)(tok0 >> 9) : (int)(tok0 >> 5);
  const int tp0 = doc ? (int)(tok0 & 511) : (int)(tok0 & 31);

  const float4* W1f4 = (const float4*)W1;   // 300x100 -> 1500 f4, 5 chunks
  const float4* W2f4 = (const float4*)W2;   // 100x300 -> 7500 f4, 5 chunks
  const float4* Wcf4 = (const float4*)Wc;   // 300x192 -> 14400 f4, 10 chunks

  float4 r0, r1, r2, r3, r4, r5;
#define LOADC(srcp, n) { const float4* _s = (srcp); \
    r0 = _s[tid]; r1 = _s[tid + 256]; r2 = _s[tid + 512]; \
    r3 = _s[tid + 768]; r4 = _s[tid + 1024]; \
    if (tid + 1280 < (n)) r5 = _s[tid + 1280]; }
#define COMMITC(n) { s_w4[tid] = r0; s_w4[tid + 256] = r1; s_w4[tid + 512] = r2; \
    s_w4[tid + 768] = r3; s_w4[tid + 1024] = r4; \
    if (tid + 1280 < (n)) s_w4[tid + 1280] = r5; }

  // prefetch chunk 0 (W1 part 0) — lands while we do init/posenc
  LOADC(W1f4, 1500);

  // ---- init: raw x -> s_A ----
  for (int i = tid; i < 1200; i += 256) {
    const float4 v = *(const float4*)(xs + (size_t)i * 4);
    const int t = i / 75, e0 = (i % 75) * 4;
    s_A[swz16(e0 + 0, t)] = v.x; s_A[swz16(e0 + 1, t)] = v.y;
    s_A[swz16(e0 + 2, t)] = v.z; s_A[swz16(e0 + 3, t)] = v.w;
  }
  __syncthreads();
  { // per-token sumsq of raw x (for xn)
    const int tk = tid & 15, ch = tid >> 4;
    const int kb = ch * 19, ke = (kb + 19 < 300) ? kb + 19 : 300;
    float ss = 0.f;
    for (int k = kb; k < ke; ++k) { const float v = s_A[swz16(k, tk)]; ss = fmaf(v, v, ss); }
    s_stat[ch][tk] = ss;
  }
  __syncthreads();
  if (tid < 16) {
    float s = 0.f;
#pragma unroll
    for (int i = 0; i < 16; ++i) s += s_stat[i][tid];
    s_norm[tid] = 1.f / (sqrtf(s) + 1e-13f);
  }
  __syncthreads();
  // ---- xn write + posenc add (in place) ----
  for (int i = tid; i < 1200; i += 256) {
    const int t = i / 75, e0 = (i % 75) * 4;
    const int tp = tp0 + t;
    const float nm = s_norm[t];
#pragma unroll
    for (int j = 0; j < 4; ++j) {
      const int e = e0 + j;
      const int slot = swz16(e, t);
      const float raw = s_A[slot];
      if (doc) dnT[((size_t)bb_ * E_ + e) * 512 + tp] = raw * nm;
      else     qn[(tok0 + t) * E_ + e] = raw * nm;
      const int f = (e < 150) ? e : e - 150;
      const float ang = __expf(-0.061814365f * (float)f) * (float)tp;
      s_A[slot] = raw + ((e < 150) ? sinf(ang) : cosf(ang));
    }
  }
  __syncthreads();   // s_A(posenc) ready

  // ---- phase 1: h1 = relu(out @ W1 + b1), chunks 0..4 (60 rows each) ----
  {
    const int cq = (ct < 25) ? ct : 24;
    float4 a1[2];
    a1[0] = make_float4(0.f, 0.f, 0.f, 0.f);
    a1[1] = make_float4(0.f, 0.f, 0.f, 0.f);
    for (int c = 0; c < 5; ++c) {
      COMMITC(1500);
      __syncthreads();
      if (c < 4) LOADC(W1f4 + 1500 * (c + 1), 1500)
      else       LOADC(W2f4, 1500)
#pragma unroll 6
      for (int kk = 0; kk < 60; ++kk) {
        const float2 xv = *(const float2*)&s_A[swz16(c * 60 + kk, t0)];
        const float4 w = s_w4[kk * 25 + cq];
        fma4(a1[0], xv.x, w); fma4(a1[1], xv.y, w);
      }
      if (c == 4 && ct < 25) {
        const float4 bb = *(const float4*)&b1[4 * ct];
#pragma unroll
        for (int rr = 0; rr < 2; ++rr) {
          const int t = t0 + rr;
          const float4 a = (rr == 0) ? a1[0] : a1[1];
          s_h1[swz16(4 * ct + 0, t)] = fmaxf(a.x + bb.x, 0.f);
          s_h1[swz16(4 * ct + 1, t)] = fmaxf(a.y + bb.y, 0.f);
          s_h1[swz16(4 * ct + 2, t)] = fmaxf(a.z + bb.z, 0.f);
          s_h1[swz16(4 * ct + 3, t)] = fmaxf(a.w + bb.w, 0.f);
        }
      }
      __syncthreads();
    }
  }

  // ---- phase 2: ff0 = h1 @ W2 + b2 + out; LN -> ff. chunks 5..9 (20 rows) --
  {
    const int q2 = (ct < 11) ? ct + 64 : 74;
    const bool val2 = (ct < 11);
    float4 a2[3][2];
#pragma unroll
    for (int p = 0; p < 3; ++p)
#pragma unroll
      for (int rr = 0; rr < 2; ++rr) a2[p][rr] = make_float4(0.f, 0.f, 0.f, 0.f);
    for (int c = 0; c < 5; ++c) {
      COMMITC(1500);
      __syncthreads();
      if (c < 4) LOADC(W2f4 + 1500 * (c + 1), 1500)
      else       LOADC(Wcf4, 1440)
#pragma unroll 5
      for (int kk = 0; kk < 20; ++kk) {
        const float2 hv = *(const float2*)&s_h1[swz16(c * 20 + kk, t0)];
        const float4 w0 = s_w4[kk * 75 + ct];
        const float4 w1 = s_w4[kk * 75 + ct + 32];
        const float4 w2 = s_w4[kk * 75 + q2];
        fma4(a2[0][0], hv.x, w0); fma4(a2[0][1], hv.y, w0);
        fma4(a2[1][0], hv.x, w1); fma4(a2[1][1], hv.y, w1);
        fma4(a2[2][0], hv.x, w2); fma4(a2[2][1], hv.y, w2);
      }
      if (c == 4) {
        // epilogue: bias + residual + LN stats + ff write (same-thread slots)
        float sum[2] = {0.f, 0.f}, sq[2] = {0.f, 0.f};
#pragma unroll
        for (int p = 0; p < 3; ++p) {
          const int qq = (p == 0) ? ct : (p == 1) ? ct + 32 : q2;
          const bool ok = (p < 2) || val2;
          if (!ok) break;
          const float4 bb = *(const float4*)&b2[4 * qq];
#pragma unroll
          for (int rr = 0; rr < 2; ++rr) {
            const int t = t0 + rr;
            float4 v = a2[p][rr];
            v.x += bb.x + s_A[swz16(4 * qq + 0, t)];
            v.y += bb.y + s_A[swz16(4 * qq + 1, t)];
            v.z += bb.z + s_A[swz16(4 * qq + 2, t)];
            v.w += bb.w + s_A[swz16(4 * qq + 3, t)];
            a2[p][rr] = v;
            sum[rr] += v.x + v.y + v.z + v.w;
            sq[rr] = fmaf(v.x, v.x, fmaf(v.y, v.y, fmaf(v.z, v.z, fmaf(v.w, v.w, sq[rr]))));
          }
        }
#pragma unroll
        for (int m = 1; m <= 16; m <<= 1) {
#pragma unroll
          for (int rr = 0; rr < 2; ++rr) {
            sum[rr] += __shfl_xor(sum[rr], m);
            sq[rr]  += __shfl_xor(sq[rr], m);
          }
        }
#pragma unroll
        for (int rr = 0; rr < 2; ++rr) {
          const int t = t0 + rr;
          const float mean = sum[rr] * (1.f / 300.f);
          const float var  = fmaxf(sq[rr] * (1.f / 300.f) - mean * mean, 0.f);
          const float rstd = 1.f / (sqrtf(var) + 1e-6f);
#pragma unroll
          for (int p = 0; p < 3; ++p) {
            if (p == 2 && !val2) break;
            const int qq = (p == 0) ? ct : (p == 1) ? ct + 32 : q2;
            const int c0 = 4 * qq;
            const float4 g4 = *(const float4*)&ffg[c0];
            const float4 b4 = *(const float4*)&ffb[c0];
            const float4 v = a2[p][rr];
            float4 fv;
            fv.x = fmaf(g4.x, (v.x - mean) * rstd, b4.x);
            fv.y = fmaf(g4.y, (v.y - mean) * rstd, b4.y);
            fv.z = fmaf(g4.z, (v.z - mean) * rstd, b4.z);
            fv.w = fmaf(g4.w, (v.w - mean) * rstd, b4.w);
            *(float4*)&ffo[(tok0 + t) * E_ + c0] = fv;
            s_A[swz16(c0 + 0, t)] = fv.x; s_A[swz16(c0 + 1, t)] = fv.y;
            s_A[swz16(c0 + 2, t)] = fv.z; s_A[swz16(c0 + 3, t)] = fv.w;
          }
        }
      }
      __syncthreads();
    }
  }

  // ---- phase 3: comb = ff @ Wc + bc. chunks 10..19 (30 rows each) ----
  {
    const int q3 = (ct < 16) ? ct + 32 : 47;
    float4 a3[2][2];
#pragma unroll
    for (int p = 0; p < 2; ++p)
#pragma unroll
      for (int rr = 0; rr < 2; ++rr) a3[p][rr] = make_float4(0.f, 0.f, 0.f, 0.f);
    for (int c = 0; c < 10; ++c) {
      COMMITC(1440);
      __syncthreads();
      if (c < 9) LOADC(Wcf4 + 1440 * (c + 1), 1440)
#pragma unroll 6
      for (int kk = 0; kk < 30; ++kk) {
        const float2 xv = *(const float2*)&s_A[swz16(c * 30 + kk, t0)];
        const float4 w0 = s_w4[kk * 48 + ct];
        const float4 w1 = s_w4[kk * 48 + q3];
        fma4(a3[0][0], xv.x, w0); fma4(a3[0][1], xv.y, w0);
        fma4(a3[1][0], xv.x, w1); fma4(a3[1][1], xv.y, w1);
      }
      if (c < 9) __syncthreads();
    }
    const float4 bb0 = *(const float4*)&bc[4 * ct];
#pragma unroll
    for (int rr = 0; rr < 2; ++rr) {
      float4 o = a3[0][rr];
      o.x += bb0.x; o.y += bb0.y; o.z += bb0.z; o.w += bb0.w;
      *(float4*)&cmo[(tok0 + t0 + rr) * CD_ + 4 * ct] = o;
    }
    if (ct < 16) {
      const float4 bb1 = *(const float4*)&bc[4 * (ct + 32)];
#pragma unroll
      for (int rr = 0; rr < 2; ++rr) {
        float4 o = a3[1][rr];
        o.x += bb1.x; o.y += bb1.y; o.z += bb1.z; o.w += bb1.w;
        *(float4*)&cmo[(tok0 + t0 + rr) * CD_ + 4 * (ct + 32)] = o;
      }
    }
  }
#undef LOADC
#undef COMMITC
}

// ---------------------------------------------------------------------------
// attention: one block per (b,h); thread = query pos. Two-pass softmax.
// ---------------------------------------------------------------------------
template <int T>
__global__ __launch_bounds__(512)
void attn(const float* __restrict__ comb, const float* __restrict__ mask,
          float* __restrict__ o)
{
  __shared__ float4 s_kv[T];  // (k0*m, k1*m, v0, v1)
  __shared__ float  s_m[T];
  const int bh = blockIdx.x, b = bh / NH_, h = bh % NH_;
  const int tid = threadIdx.x;
  const float* cb = comb + (size_t)b * T * CD_;
  if (tid < T) {
    const float* c = cb + (size_t)tid * CD_;
    const float m = mask[b * T + tid];
    s_kv[tid] = make_float4(c[AD_ + 2 * h] * m, c[AD_ + 2 * h + 1] * m,
                            c[2 * AD_ + 2 * h], c[2 * AD_ + 2 * h + 1]);
    s_m[tid] = m;
  }
  __syncthreads();
  if (tid < T) {
    const float* c = cb + (size_t)tid * CD_;
    const float q0 = c[2 * h] * (1.f / 3.f);
    const float q1 = c[2 * h + 1] * (1.f / 3.f);
    float M = -1e30f;
    for (int j = 0; j < T; ++j) {
      const float4 kv = s_kv[j];
      M = fmaxf(M, fmaf(q0, kv.x, q1 * kv.y));
    }
    float S = 0.f, W = 0.f, a0 = 0.f, a1 = 0.f;
    for (int j = 0; j < T; ++j) {
      const float4 kv = s_kv[j];
      const float s = fmaf(q0, kv.x, q1 * kv.y);
      const float z = __expf(s - M);
      const float w = z * s_m[j];
      S += z; W += w;
      a0 = fmaf(w, kv.z, a0);
      a1 = fmaf(w, kv.w, a1);
    }
    const float dn = 1.f / (W + 1e-13f * S);
    float* op = o + (size_t)(b * T + tid) * AD_ + 2 * h;
    op[0] = a0 * dn;
    op[1] = a1 * dn;
  }
}

// ---------------------------------------------------------------------------
// encode_back_v8: merged doc+query, 16 tokens/block, Wo chunked via single
// 19.2 KB LDS buffer + T14 register prefetch (4 chunks of 16 rows).
// ---------------------------------------------------------------------------
__global__ __launch_bounds__(256)
void encode_back_v8(const float* __restrict__ oq, const float* __restrict__ od,
                    const float* __restrict__ ffq, const float* __restrict__ ffd,
                    const float* __restrict__ Wo, const float* __restrict__ bo,
                    const float* __restrict__ lng, const float* __restrict__ lnb,
                    const float* __restrict__ qm, const float* __restrict__ dm,
                    float* __restrict__ qctx, float* __restrict__ dctxT)
{
  __shared__ float  s_O[1024];     // o transposed+swizzled [c][16]
  __shared__ float4 s_wb[1200];    // Wo chunk buffer (19.2 KB, single)

  const int tid = threadIdx.x;
  const int ct = tid & 31, tg = tid >> 5;
  const int t0 = tg * 2;
  const bool doc = (blockIdx.x < DOCBLK_);
  const int sb = doc ? blockIdx.x : (blockIdx.x - DOCBLK_);
  const size_t tok0 = (size_t)sb * 16;
  const float* op = doc ? od : oq;
  const float* ffp = doc ? ffd : ffq;
  const float* mp = doc ? dm : qm;
  const int bb_ = doc ? (int)(tok0 >> 9) : 0;
  const int tp0 = doc ? (int)(tok0 & 511) : 0;

  const float4* Wof4 = (const float4*)Wo;   // 64x300 -> 4800 f4, 4 chunks x 1200

  float4 r0, r1, r2, r3, r4;
#define LOADB(srcp) { const float4* _s = (srcp); \
    r0 = _s[tid]; r1 = _s[tid + 256]; r2 = _s[tid + 512]; r3 = _s[tid + 768]; \
    if (tid + 1024 < 1200) r4 = _s[tid + 1024]; }
#define COMMITB() { s_wb[tid] = r0; s_wb[tid + 256] = r1; s_wb[tid + 512] = r2; \
    s_wb[tid + 768] = r3; if (tid + 1024 < 1200) s_wb[tid + 1024] = r4; }

  LOADB(Wof4);

  { // load o (16x64) transposed into s_O
    const int t = tid >> 4, c0 = (tid & 15) * 4;
    const float4 v = *(const float4*)(op + (tok0 + t) * AD_ + c0);
    s_O[swz16(c0 + 0, t)] = v.x; s_O[swz16(c0 + 1, t)] = v.y;
    s_O[swz16(c0 + 2, t)] = v.z; s_O[swz16(c0 + 3, t)] = v.w;
  }
  __syncthreads();

  const int q2 = (ct < 11) ? ct + 64 : 74;
  const bool val2 = (ct < 11);
  float4 a[3][2];
#pragma unroll
  for (int p = 0; p < 3; ++p)
#pragma unroll
    for (int rr = 0; rr < 2; ++rr) a[p][rr] = make_float4(0.f, 0.f, 0.f, 0.f);
  for (int c = 0; c < 4; ++c) {
    COMMITB();
    __syncthreads();
    if (c < 3) LOADB(Wof4 + 1200 * (c + 1))
#pragma unroll 4
    for (int kk = 0; kk < 16; ++kk) {
      const float2 ov = *(const float2*)&s_O[swz16(c * 16 + kk, t0)];
      const float4 w0 = s_wb[kk * 75 + ct];
      const float4 w1 = s_wb[kk * 75 + ct + 32];
      const float4 w2 = s_wb[kk * 75 + q2];
      fma4(a[0][0], ov.x, w0); fma4(a[0][1], ov.y, w0);
      fma4(a[1][0], ov.x, w1); fma4(a[1][1], ov.y, w1);
      fma4(a[2][0], ov.x, w2); fma4(a[2][1], ov.y, w2);
    }
    if (c < 3) __syncthreads();
  }
  // residual + LN stats
  float sum[2] = {0.f, 0.f}, sq[2] = {0.f, 0.f};
#pragma unroll
  for (int p = 0; p < 3; ++p) {
    const int qq = (p == 0) ? ct : (p == 1) ? ct + 32 : q2;
    const bool ok = (p < 2) || val2;
    if (!ok) break;
    const float4 bb = *(const float4*)&bo[4 * qq];
#pragma unroll
    for (int rr = 0; rr < 2; ++rr) {
      const int t = t0 + rr;
      const float4 f4 = *(const float4*)(ffp + (tok0 + t) * E_ + 4 * qq);
      float4 v = a[p][rr];
      v.x += bb.x + f4.x; v.y += bb.y + f4.y;
      v.z += bb.z + f4.z; v.w += bb.w + f4.w;
      a[p][rr] = v;
      sum[rr] += v.x + v.y + v.z + v.w;
      sq[rr] = fmaf(v.x, v.x, fmaf(v.y, v.y, fmaf(v.z, v.z, fmaf(v.w, v.w, sq[rr]))));
    }
  }
#pragma unroll
  for (int m = 1; m <= 16; m <<= 1) {
#pragma unroll
    for (int rr = 0; rr < 2; ++rr) {
      sum[rr] += __shfl_xor(sum[rr], m);
      sq[rr]  += __shfl_xor(sq[rr], m);
    }
  }
#pragma unroll
  for (int rr = 0; rr < 2; ++rr) {
    const int t = t0 + rr;
    const float mean = sum[rr] * (1.f / 300.f);
    const float var  = fmaxf(sq[rr] * (1.f / 300.f) - mean * mean, 0.f);
    const float rstd = 1.f / (sqrtf(var) + 1e-6f);
    const float mk = mp[tok0 + t];
#pragma unroll
    for (int p = 0; p < 3; ++p) {
      if (p == 2 && !val2) break;
      const int qq = (p == 0) ? ct : (p == 1) ? ct + 32 : q2;
      const int c0 = 4 * qq;
      const float4 g4 = *(const float4*)&lng[c0];
      const float4 b4 = *(const float4*)&lnb[c0];
      const float4 v = a[p][rr];
      float4 fv;
      fv.x = fmaf(g4.x, (v.x - mean) * rstd, b4.x) * mk;
      fv.y = fmaf(g4.y, (v.y - mean) * rstd, b4.y) * mk;
      fv.z = fmaf(g4.z, (v.z - mean) * rstd, b4.z) * mk;
      fv.w = fmaf(g4.w, (v.w - mean) * rstd, b4.w) * mk;
      if (doc) {
        const int tp = tp0 + t;
        dctxT[((size_t)bb_ * E_ + c0 + 0) * 512 + tp] = fv.x;
        dctxT[((size_t)bb_ * E_ + c0 + 1) * 512 + tp] = fv.y;
        dctxT[((size_t)bb_ * E_ + c0 + 2) * 512 + tp] = fv.z;
        dctxT[((size_t)bb_ * E_ + c0 + 3) * 512 + tp] = fv.w;
      } else {
        *(float4*)&qctx[(tok0 + t) * E_ + c0] = fv;
      }
    }
  }
#undef LOADB
#undef COMMITB
}

// ---------------------------------------------------------------------------
// simtanh_v2: 256 blocks (b,qh,dc: 16x2x8) x 512 threads (epart=wave 0..7,
// dlane 0..63). Partial dots + LDS reduce, tanh, coalesced store.
// ---------------------------------------------------------------------------
__global__ __launch_bounds__(512)
void simtanh_v2(const float* __restrict__ qctx, const float* __restrict__ qn,
                const float* __restrict__ dctxT, const float* __restrict__ dnT,
                float* __restrict__ combined)
{
  __shared__ float s_q[2 * 16 * 304];     // [type][q][e]
  __shared__ float s_part[8 * 32 * 64];   // [epart][q*2+type][dlane]

  const int bid = blockIdx.x;
  const int sub = bid & 15, b = bid >> 4;
  const int qh = sub >> 3, dc = sub & 7;
  const int tid = threadIdx.x;
  const int ep = tid >> 6, dlane = tid & 63;
  const int d = dc * 64 + dlane;

  const float* qc  = qctx + ((size_t)b * 32 + qh * 16) * E_;
  const float* qnp = qn   + ((size_t)b * 32 + qh * 16) * E_;
  for (int i = tid; i < 1200; i += 512) {
    const int q = i / 75, e0 = (i % 75) * 4;
    *(float4*)&s_q[(0 * 16 + q) * 304 + e0] = *(const float4*)(qc + q * E_ + e0);
    *(float4*)&s_q[(1 * 16 + q) * 304 + e0] = *(const float4*)(qnp + q * E_ + e0);
  }
  __syncthreads();

  const float* dct = dctxT + (size_t)b * E_ * 512 + d;
  const float* dnt = dnT   + (size_t)b * E_ * 512 + d;
  float accD[16], accC[16];
#pragma unroll
  for (int q = 0; q < 16; ++q) { accD[q] = 0.f; accC[q] = 0.f; }
  const int es = ep * 40, ee = (es + 40 < 300) ? es + 40 : 300;
  for (int e0 = es; e0 < ee; e0 += 4) {
    const float dv0 = dct[(size_t)(e0 + 0) * 512];
    const float dv1 = dct[(size_t)(e0 + 1) * 512];
    const float dv2 = dct[(size_t)(e0 + 2) * 512];
    const float dv3 = dct[(size_t)(e0 + 3) * 512];
    const float dn0 = dnt[(size_t)(e0 + 0) * 512];
    const float dn1 = dnt[(size_t)(e0 + 1) * 512];
    const float dn2 = dnt[(size_t)(e0 + 2) * 512];
    const float dn3 = dnt[(size_t)(e0 + 3) * 512];
#pragma unroll
    for (int q = 0; q < 16; ++q) {
      const float4 qd = *(const float4*)&s_q[(0 * 16 + q) * 304 + e0];
      const float4 qc4 = *(const float4*)&s_q[(1 * 16 + q) * 304 + e0];
      float aD = accD[q], aC = accC[q];
      aD = fmaf(qd.x, dv0, aD); aD = fmaf(qd.y, dv1, aD);
      aD = fmaf(qd.z, dv2, aD); aD = fmaf(qd.w, dv3, aD);
      aC = fmaf(qc4.x, dn0, aC); aC = fmaf(qc4.y, dn1, aC);
      aC = fmaf(qc4.z, dn2, aC); aC = fmaf(qc4.w, dn3, aC);
      accD[q] = aD; accC[q] = aC;
    }
  }
#pragma unroll
  for (int q = 0; q < 16; ++q) {
    s_part[(ep * 32 + q * 2 + 0) * 64 + dlane] = accC[q];  // cos
    s_part[(ep * 32 + q * 2 + 1) * 64 + dlane] = accD[q];  // dot
  }
  __syncthreads();
  const int s0 = (tid >> 6) * 4;
#pragma unroll
  for (int si = 0; si < 4; ++si) {
    const int s = s0 + si;
    float v = 0.f;
#pragma unroll
    for (int p = 0; p < 8; ++p) v += s_part[(p * 32 + s) * 64 + dlane];
    const int q = s >> 1, typ = s & 1;
    combined[(((size_t)b * 2 + typ) * 32 + qh * 16 + q) * 512 + d] = tanhf(v);
  }
}

// ---------------------------------------------------------------------------
// conv_all: 5 convs (k=1..5, end-padded) + channel-max -> (B,5,32,512).
// Results stored immediately (keeps register pressure one-conv-wide; the
// fused variant spilled to scratch — 2.5 GB/dispatch HBM traffic, R6).
// ---------------------------------------------------------------------------
template <int K>
__device__ __forceinline__ float conv_max16(const float* __restrict__ s_in, int j,
                                            const float* __restrict__ w,
                                            const float* __restrict__ bias)
{
  float patch[2][K][K];
#pragma unroll
  for (int c = 0; c < 2; ++c)
#pragma unroll
    for (int di = 0; di < K; ++di)
#pragma unroll
      for (int dj = 0; dj < K; ++dj)
        patch[c][di][dj] = s_in[(c * 5 + di) * 516 + j + dj];
  float best = -1e30f;
#pragma unroll
  for (int oc = 0; oc < 16; ++oc) {
    float acc = bias[oc];
#pragma unroll
    for (int c = 0; c < 2; ++c)
#pragma unroll
      for (int di = 0; di < K; ++di)
#pragma unroll
        for (int dj = 0; dj < K; ++dj)
          acc = fmaf(patch[c][di][dj], w[((oc * 2 + c) * K + di) * K + dj], acc);
    best = fmaxf(best, acc);
  }
  return best;
}

__global__ __launch_bounds__(512)
void conv_all(const float* __restrict__ combined,
              const float* __restrict__ c1w, const float* __restrict__ c1b,
              const float* __restrict__ c2w, const float* __restrict__ c2b,
              const float* __restrict__ c3w, const float* __restrict__ c3b,
              const float* __restrict__ c4w, const float* __restrict__ c4b,
              const float* __restrict__ c5w, const float* __restrict__ c5b,
              float* __restrict__ convout)
{
  __shared__ float s_in[2 * 5 * 516];
  __shared__ float s_w[1730];
  __shared__ float s_b[66];
  const int blk = blockIdx.x, b = blk >> 5, i = blk & 31;
  const int tid = threadIdx.x;
  for (int idx = tid; idx < 2 * 5 * 516; idx += 512) {
    const int c = idx / (5 * 516), rem = idx % (5 * 516), r = rem / 516, j = rem % 516;
    const int row = i + r;
    float v = 0.f;
    if (row < 32 && j < 512)
      v = combined[((size_t)(b * 2 + c) * 32 + row) * 512 + j];
    s_in[idx] = v;
  }
  if (tid < 2)   s_w[tid] = c1w[tid];
  if (tid < 128) s_w[2 + tid] = c2w[tid];
  if (tid < 288) s_w[130 + tid] = c3w[tid];
  s_w[418 + tid] = c4w[tid];
  for (int idx = tid; idx < 800; idx += 512) s_w[930 + idx] = c5w[idx];
  if (tid == 0) s_b[0] = c1b[0];
  if (tid < 16) {
    s_b[1 + tid]  = c2b[tid];
    s_b[17 + tid] = c3b[tid];
    s_b[33 + tid] = c4b[tid];
    s_b[49 + tid] = c5b[tid];
  }
  __syncthreads();
  const int j = tid;
  const float o1 = fmaf(s_in[j], s_w[0], fmaf(s_in[5 * 516 + j], s_w[1], s_b[0]));
  convout[((size_t)(b * 5 + 0) * 32 + i) * 512 + j] = o1;
  convout[((size_t)(b * 5 + 1) * 32 + i) * 512 + j] = conv_max16<2>(s_in, j, s_w + 2,   s_b + 1);
  convout[((size_t)(b * 5 + 2) * 32 + i) * 512 + j] = conv_max16<3>(s_in, j, s_w + 130, s_b + 17);
  convout[((size_t)(b * 5 + 3) * 32 + i) * 512 + j] = conv_max16<4>(s_in, j, s_w + 418, s_b + 33);
  convout[((size_t)(b * 5 + 4) * 32 + i) * 512 + j] = conv_max16<5>(s_in, j, s_w + 930, s_b + 49);
}

// ---------------------------------------------------------------------------
// rbf_pkq
// ---------------------------------------------------------------------------
__global__ __launch_bounds__(512)
void rbf_pkq(const float* __restrict__ convout, const float* __restrict__ dmask,
             const float* __restrict__ qmask, float* __restrict__ pkq)
{
  __shared__ float red[8][NK_];
  const int id = blockIdx.x;
  const int q = id & 31;
  const int b = id / 160;
  const int tid = threadIdx.x;
  const float x = convout[(size_t)id * 512 + tid];
  const float dmv = dmask[b * 512 + tid];
  const float mu[NK_]  = {1.f, .9f, .7f, .5f, .3f, .1f, -.1f, -.3f, -.5f, -.7f, -.9f};
  const float nis[NK_] = {-5e7f, -50.f, -50.f, -50.f, -50.f, -50.f,
                          -50.f, -50.f, -50.f, -50.f, -50.f};
  const int lane = tid & 63, w = tid >> 6;
#pragma unroll
  for (int k = 0; k < NK_; ++k) {
    const float df = x - mu[k];
    float v = __expf(df * df * nis[k]) * dmv;
    v = wave_sum(v);
    if (lane == 0) red[w][k] = v;
  }
  __syncthreads();
  if (tid < NK_) {
    float s = 0.f;
#pragma unroll
    for (int ww = 0; ww < 8; ++ww) s += red[ww][tid];
    pkq[(size_t)id * NK_ + tid] = s * qmask[b * 32 + q];
  }
}

// ---------------------------------------------------------------------------
// final_k
// ---------------------------------------------------------------------------
__global__ __launch_bounds__(64)
void final_k(const float* __restrict__ pkq, const float* __restrict__ qmask,
             const float* __restrict__ dmask,
             const float* __restrict__ dw, const float* __restrict__ db,
             const float* __restrict__ dmw, const float* __restrict__ dmb,
             const float* __restrict__ cw, float* __restrict__ out)
{
  const int b = blockIdx.x, tid = threadIdx.x;
  float dl = 0.f;
  for (int j = tid; j < 512; j += 64) dl += dmask[b * 512 + j];
  dl = wave_sum(dl);
  dl = __shfl(dl, 0);
  float v1 = 0.f, v2 = 0.f;
  if (tid < 55) {
    const int c = tid / NK_, k = tid % NK_;
    const float rdl = 1.f / dl;
    float s1 = 0.f, s2 = 0.f;
    for (int q = 0; q < 32; ++q) {
      const float p = pkq[(size_t)((b * 5 + c) * 32 + q) * NK_ + k];
      const float qmv = qmask[b * 32 + q];
      s1 += logf(fmaxf(p, 1e-10f)) * qmv;
      s2 += logf(fmaxf(p * rdl, 1e-10f)) * qmv;
    }
    v1 = s1 * dw[tid];
    v2 = s2 * dmw[tid];
  }
  v1 = wave_sum(v1);
  v2 = wave_sum(v2);
  if (tid == 0) out[b] = (v1 + db[0]) * cw[0] + (v2 + dmb[0]) * cw[1];
}

}  // namespace

extern "C" void kernel_launch(void* const* d_in, const int* in_sizes, int n_in,
                              void* d_out, int out_size, void* d_ws, size_t ws_size,
                              hipStream_t stream)
{
  const float* qe  = (const float*)d_in[0];
  const float* de  = (const float*)d_in[1];
  const float* qm  = (const float*)d_in[2];
  const float* dm  = (const float*)d_in[3];
  const float* W1  = (const float*)d_in[6];
  const float* b1  = (const float*)d_in[7];
  const float* W2  = (const float*)d_in[8];
  const float* b2  = (const float*)d_in[9];
  const float* ffg = (const float*)d_in[10];
  const float* ffb = (const float*)d_in[11];
  const float* Wc  = (const float*)d_in[12];
  const float* bc  = (const float*)d_in[13];
  const float* Wo  = (const float*)d_in[14];
  const float* bo  = (const float*)d_in[15];
  const float* lng = (const float*)d_in[16];
  const float* lnb = (const float*)d_in[17];
  const float* c1w = (const float*)d_in[18];
  const float* c1b = (const float*)d_in[19];
  const float* c2w = (const float*)d_in[20];
  const float* c2b = (const float*)d_in[21];
  const float* c3w = (const float*)d_in[22];
  const float* c3b = (const float*)d_in[23];
  const float* c4w = (const float*)d_in[24];
  const float* c4b = (const float*)d_in[25];
  const float* c5w = (const float*)d_in[26];
  const float* c5b = (const float*)d_in[27];
  const float* dwp  = (const float*)d_in[28];
  const float* dbp  = (const float*)d_in[29];
  const float* dmwp = (const float*)d_in[30];
  const float* dmbp = (const float*)d_in[31];
  const float* cwp  = (const float*)d_in[32];

  float* ws = (float*)d_ws;
  size_t off = 0;
  auto alloc = [&](size_t n) { float* p = ws + off; off += n; return p; };
  float* ffq      = alloc((size_t)B_ * TQ_ * E_);
  float* combq    = alloc((size_t)B_ * TQ_ * CD_);
  float* oq       = alloc((size_t)B_ * TQ_ * AD_);
  float* qctx     = alloc((size_t)B_ * TQ_ * E_);
  float* qn       = alloc((size_t)B_ * TQ_ * E_);
  float* ffd      = alloc((size_t)B_ * TD_ * E_);
  float* combd    = alloc((size_t)B_ * TD_ * CD_);
  float* od       = alloc((size_t)B_ * TD_ * AD_);
  float* dctxT    = alloc((size_t)B_ * E_ * TD_);
  float* dnT      = alloc((size_t)B_ * E_ * TD_);
  float* combined = alloc((size_t)B_ * 2 * TQ_ * TD_);
  float* convout  = alloc((size_t)B_ * 5 * TQ_ * TD_);
  float* pkq      = alloc((size_t)B_ * 5 * TQ_ * NK_);

  encode_front_v8<<<DOCBLK_ + 32, 256, 0, stream>>>(
      qe, de, W1, b1, W2, b2, ffg, ffb, Wc, bc,
      ffq, combq, qn, ffd, combd, dnT);
  attn<TQ_><<<B_ * NH_, 64, 0, stream>>>(combq, qm, oq);
  attn<TD_><<<B_ * NH_, 512, 0, stream>>>(combd, dm, od);
  encode_back_v8<<<DOCBLK_ + 32, 256, 0, stream>>>(
      oq, od, ffq, ffd, Wo, bo, lng, lnb, qm, dm, qctx, dctxT);
  simtanh_v2<<<256, 512, 0, stream>>>(qctx, qn, dctxT, dnT, combined);
  conv_all<<<B_ * 32, 512, 0, stream>>>(
      combined, c1w, c1b, c2w, c2b, c3w, c3b, c4w, c4b, c5w, c5b, convout);
  rbf_pkq<<<B_ * 5 * TQ_, 512, 0, stream>>>(convout, dm, qm, pkq);
  final_k<<<B_, 64, 0, stream>>>(pkq, qm, dm, dwp, dbp, dmwp, dmbp, cwp,
                                 (float*)d_out);
}

// Round 9
// 329.689 us; speedup vs baseline: 3.5988x; 1.1110x over previous
//
#include <hip/hip_runtime.h>

namespace {

constexpr int E_  = 300;
constexpr int FF_ = 100;
constexpr int AD_ = 64;
constexpr int NH_ = 32;
constexpr int CD_ = 192;   // 3*AD
constexpr int B_  = 16;
constexpr int TQ_ = 32;
constexpr int TD_ = 512;
constexpr int NK_ = 11;
constexpr int DOCBLK_ = 512;   // 8192 doc tokens / 16 per block

__device__ __forceinline__ float wave_sum(float v) {
#pragma unroll
  for (int o = 32; o > 0; o >>= 1) v += __shfl_down(v, o);
  return v;
}

// swizzled transposed activation slot: [e][t], t in 0..15; XOR on bits>=1 so
// even token pairs stay contiguous (b64 reads), banks spread for col reads.
__device__ __forceinline__ int swz16(int e, int t) {
  return e * 16 + (t ^ (((e >> 2) & 7) << 1));
}

__device__ __forceinline__ void fma4(float4& a, float s, const float4& w) {
  a.x = fmaf(s, w.x, a.x); a.y = fmaf(s, w.y, a.y);
  a.z = fmaf(s, w.z, a.z); a.w = fmaf(s, w.w, a.w);
}

// ---------------------------------------------------------------------------
// encode_front_v8: 16 tok/block, 256 thr, 2 tok per thread, LDS-chunked
// weights + T14 async-stage split (prefetch chunk c+1 into registers during
// compute of chunk c; commit to single 24 KB LDS buffer next iteration).
// ---------------------------------------------------------------------------
__global__ __launch_bounds__(256)
void encode_front_v8(const float* __restrict__ qe, const float* __restrict__ de,
                     const float* __restrict__ W1, const float* __restrict__ b1,
                     const float* __restrict__ W2, const float* __restrict__ b2,
                     const float* __restrict__ ffg, const float* __restrict__ ffb,
                     const float* __restrict__ Wc, const float* __restrict__ bc,
                     float* __restrict__ ffq, float* __restrict__ combq,
                     float* __restrict__ qn,
                     float* __restrict__ ffd, float* __restrict__ combd,
                     float* __restrict__ dnT)
{
  __shared__ float  s_A[4800];    // x / ff transposed+swizzled [e][16]
  __shared__ float  s_h1[1600];   // h1 transposed+swizzled     [c][16]
  __shared__ float4 s_w4[1500];   // weight chunk buffer (24 KB, single)
  __shared__ float  s_stat[16][17];
  __shared__ float  s_norm[16];

  const int tid = threadIdx.x;
  const int ct = tid & 31, tg = tid >> 5;
  const int t0 = tg * 2;
  const bool doc = (blockIdx.x < DOCBLK_);
  const int sb = doc ? blockIdx.x : (blockIdx.x - DOCBLK_);
  const float* xs = (doc ? de : qe) + (size_t)sb * 16 * E_;
  float* ffo = doc ? ffd : ffq;
  float* cmo = doc ? combd : combq;
  const size_t tok0 = (size_t)sb * 16;
  const int bb_ = doc ? (int)(tok0 >> 9) : (int)(tok0 >> 5);
  const int tp0 = doc ? (int)(tok0 & 511) : (int)(tok0 & 31);

  const float4* W1f4 = (const float4*)W1;   // 300x100 -> 1500 f4, 5 chunks
  const float4* W2f4 = (const float4*)W2;   // 100x300 -> 7500 f4, 5 chunks
  const float4* Wcf4 = (const float4*)Wc;   // 300x192 -> 14400 f4, 10 chunks

  float4 r0, r1, r2, r3, r4, r5;
#define LOADC(srcp, n) { const float4* _s = (srcp); \
    r0 = _s[tid]; r1 = _s[tid + 256]; r2 = _s[tid + 512]; \
    r3 = _s[tid + 768]; r4 = _s[tid + 1024]; \
    if (tid + 1280 < (n)) r5 = _s[tid + 1280]; }
#define COMMITC(n) { s_w4[tid] = r0; s_w4[tid + 256] = r1; s_w4[tid + 512] = r2; \
    s_w4[tid + 768] = r3; s_w4[tid + 1024] = r4; \
    if (tid + 1280 < (n)) s_w4[tid + 1280] = r5; }

  // prefetch chunk 0 (W1 part 0) — lands while we do init/posenc
  LOADC(W1f4, 1500);

  // ---- init: raw x -> s_A ----
  for (int i = tid; i < 1200; i += 256) {
    const float4 v = *(const float4*)(xs + (size_t)i * 4);
    const int t = i / 75, e0 = (i % 75) * 4;
    s_A[swz16(e0 + 0, t)] = v.x; s_A[swz16(e0 + 1, t)] = v.y;
    s_A[swz16(e0 + 2, t)] = v.z; s_A[swz16(e0 + 3, t)] = v.w;
  }
  __syncthreads();
  { // per-token sumsq of raw x (for xn)
    const int tk = tid & 15, ch = tid >> 4;
    const int kb = ch * 19, ke = (kb + 19 < 300) ? kb + 19 : 300;
    float ss = 0.f;
    for (int k = kb; k < ke; ++k) { const float v = s_A[swz16(k, tk)]; ss = fmaf(v, v, ss); }
    s_stat[ch][tk] = ss;
  }
  __syncthreads();
  if (tid < 16) {
    float s = 0.f;
#pragma unroll
    for (int i = 0; i < 16; ++i) s += s_stat[i][tid];
    s_norm[tid] = 1.f / (sqrtf(s) + 1e-13f);
  }
  __syncthreads();
  // ---- xn write + posenc add (in place) ----
  for (int i = tid; i < 1200; i += 256) {
    const int t = i / 75, e0 = (i % 75) * 4;
    const int tp = tp0 + t;
    const float nm = s_norm[t];
#pragma unroll
    for (int j = 0; j < 4; ++j) {
      const int e = e0 + j;
      const int slot = swz16(e, t);
      const float raw = s_A[slot];
      if (doc) dnT[((size_t)bb_ * E_ + e) * 512 + tp] = raw * nm;
      else     qn[(tok0 + t) * E_ + e] = raw * nm;
      const int f = (e < 150) ? e : e - 150;
      const float ang = __expf(-0.061814365f * (float)f) * (float)tp;
      s_A[slot] = raw + ((e < 150) ? sinf(ang) : cosf(ang));
    }
  }
  __syncthreads();   // s_A(posenc) ready

  // ---- phase 1: h1 = relu(out @ W1 + b1), chunks 0..4 (60 rows each) ----
  {
    const int cq = (ct < 25) ? ct : 24;
    float4 a1[2];
    a1[0] = make_float4(0.f, 0.f, 0.f, 0.f);
    a1[1] = make_float4(0.f, 0.f, 0.f, 0.f);
    for (int c = 0; c < 5; ++c) {
      COMMITC(1500);
      __syncthreads();
      if (c < 4) LOADC(W1f4 + 1500 * (c + 1), 1500)
      else       LOADC(W2f4, 1500)
#pragma unroll 6
      for (int kk = 0; kk < 60; ++kk) {
        const float2 xv = *(const float2*)&s_A[swz16(c * 60 + kk, t0)];
        const float4 w = s_w4[kk * 25 + cq];
        fma4(a1[0], xv.x, w); fma4(a1[1], xv.y, w);
      }
      if (c == 4 && ct < 25) {
        const float4 bb = *(const float4*)&b1[4 * ct];
#pragma unroll
        for (int rr = 0; rr < 2; ++rr) {
          const int t = t0 + rr;
          const float4 a = (rr == 0) ? a1[0] : a1[1];
          s_h1[swz16(4 * ct + 0, t)] = fmaxf(a.x + bb.x, 0.f);
          s_h1[swz16(4 * ct + 1, t)] = fmaxf(a.y + bb.y, 0.f);
          s_h1[swz16(4 * ct + 2, t)] = fmaxf(a.z + bb.z, 0.f);
          s_h1[swz16(4 * ct + 3, t)] = fmaxf(a.w + bb.w, 0.f);
        }
      }
      __syncthreads();
    }
  }

  // ---- phase 2: ff0 = h1 @ W2 + b2 + out; LN -> ff. chunks 5..9 (20 rows) --
  {
    const int q2 = (ct < 11) ? ct + 64 : 74;
    const bool val2 = (ct < 11);
    float4 a2[3][2];
#pragma unroll
    for (int p = 0; p < 3; ++p)
#pragma unroll
      for (int rr = 0; rr < 2; ++rr) a2[p][rr] = make_float4(0.f, 0.f, 0.f, 0.f);
    for (int c = 0; c < 5; ++c) {
      COMMITC(1500);
      __syncthreads();
      if (c < 4) LOADC(W2f4 + 1500 * (c + 1), 1500)
      else       LOADC(Wcf4, 1440)
#pragma unroll 5
      for (int kk = 0; kk < 20; ++kk) {
        const float2 hv = *(const float2*)&s_h1[swz16(c * 20 + kk, t0)];
        const float4 w0 = s_w4[kk * 75 + ct];
        const float4 w1 = s_w4[kk * 75 + ct + 32];
        const float4 w2 = s_w4[kk * 75 + q2];
        fma4(a2[0][0], hv.x, w0); fma4(a2[0][1], hv.y, w0);
        fma4(a2[1][0], hv.x, w1); fma4(a2[1][1], hv.y, w1);
        fma4(a2[2][0], hv.x, w2); fma4(a2[2][1], hv.y, w2);
      }
      if (c == 4) {
        // epilogue: bias + residual + LN stats + ff write (same-thread slots)
        float sum[2] = {0.f, 0.f}, sq[2] = {0.f, 0.f};
#pragma unroll
        for (int p = 0; p < 3; ++p) {
          const int qq = (p == 0) ? ct : (p == 1) ? ct + 32 : q2;
          const bool ok = (p < 2) || val2;
          if (!ok) break;
          const float4 bb = *(const float4*)&b2[4 * qq];
#pragma unroll
          for (int rr = 0; rr < 2; ++rr) {
            const int t = t0 + rr;
            float4 v = a2[p][rr];
            v.x += bb.x + s_A[swz16(4 * qq + 0, t)];
            v.y += bb.y + s_A[swz16(4 * qq + 1, t)];
            v.z += bb.z + s_A[swz16(4 * qq + 2, t)];
            v.w += bb.w + s_A[swz16(4 * qq + 3, t)];
            a2[p][rr] = v;
            sum[rr] += v.x + v.y + v.z + v.w;
            sq[rr] = fmaf(v.x, v.x, fmaf(v.y, v.y, fmaf(v.z, v.z, fmaf(v.w, v.w, sq[rr]))));
          }
        }
#pragma unroll
        for (int m = 1; m <= 16; m <<= 1) {
#pragma unroll
          for (int rr = 0; rr < 2; ++rr) {
            sum[rr] += __shfl_xor(sum[rr], m);
            sq[rr]  += __shfl_xor(sq[rr], m);
          }
        }
#pragma unroll
        for (int rr = 0; rr < 2; ++rr) {
          const int t = t0 + rr;
          const float mean = sum[rr] * (1.f / 300.f);
          const float var  = fmaxf(sq[rr] * (1.f / 300.f) - mean * mean, 0.f);
          const float rstd = 1.f / (sqrtf(var) + 1e-6f);
#pragma unroll
          for (int p = 0; p < 3; ++p) {
            if (p == 2 && !val2) break;
            const int qq = (p == 0) ? ct : (p == 1) ? ct + 32 : q2;
            const int c0 = 4 * qq;
            const float4 g4 = *(const float4*)&ffg[c0];
            const float4 b4 = *(const float4*)&ffb[c0];
            const float4 v = a2[p][rr];
            float4 fv;
            fv.x = fmaf(g4.x, (v.x - mean) * rstd, b4.x);
            fv.y = fmaf(g4.y, (v.y - mean) * rstd, b4.y);
            fv.z = fmaf(g4.z, (v.z - mean) * rstd, b4.z);
            fv.w = fmaf(g4.w, (v.w - mean) * rstd, b4.w);
            *(float4*)&ffo[(tok0 + t) * E_ + c0] = fv;
            s_A[swz16(c0 + 0, t)] = fv.x; s_A[swz16(c0 + 1, t)] = fv.y;
            s_A[swz16(c0 + 2, t)] = fv.z; s_A[swz16(c0 + 3, t)] = fv.w;
          }
        }
      }
      __syncthreads();
    }
  }

  // ---- phase 3: comb = ff @ Wc + bc. chunks 10..19 (30 rows each) ----
  {
    const int q3 = (ct < 16) ? ct + 32 : 47;
    float4 a3[2][2];
#pragma unroll
    for (int p = 0; p < 2; ++p)
#pragma unroll
      for (int rr = 0; rr < 2; ++rr) a3[p][rr] = make_float4(0.f, 0.f, 0.f, 0.f);
    for (int c = 0; c < 10; ++c) {
      COMMITC(1440);
      __syncthreads();
      if (c < 9) LOADC(Wcf4 + 1440 * (c + 1), 1440)
#pragma unroll 6
      for (int kk = 0; kk < 30; ++kk) {
        const float2 xv = *(const float2*)&s_A[swz16(c * 30 + kk, t0)];
        const float4 w0 = s_w4[kk * 48 + ct];
        const float4 w1 = s_w4[kk * 48 + q3];
        fma4(a3[0][0], xv.x, w0); fma4(a3[0][1], xv.y, w0);
        fma4(a3[1][0], xv.x, w1); fma4(a3[1][1], xv.y, w1);
      }
      if (c < 9) __syncthreads();
    }
    const float4 bb0 = *(const float4*)&bc[4 * ct];
#pragma unroll
    for (int rr = 0; rr < 2; ++rr) {
      float4 o = a3[0][rr];
      o.x += bb0.x; o.y += bb0.y; o.z += bb0.z; o.w += bb0.w;
      *(float4*)&cmo[(tok0 + t0 + rr) * CD_ + 4 * ct] = o;
    }
    if (ct < 16) {
      const float4 bb1 = *(const float4*)&bc[4 * (ct + 32)];
#pragma unroll
      for (int rr = 0; rr < 2; ++rr) {
        float4 o = a3[1][rr];
        o.x += bb1.x; o.y += bb1.y; o.z += bb1.z; o.w += bb1.w;
        *(float4*)&cmo[(tok0 + t0 + rr) * CD_ + 4 * (ct + 32)] = o;
      }
    }
  }
#undef LOADC
#undef COMMITC
}

// ---------------------------------------------------------------------------
// attn_all: doc (blocks 0..511, T=512) + query (blocks 512..1023, T=32)
// merged. Single-pass softmax with M=0: scores are O(1) (LN'ed activations,
// 0.05-scale weights), so exp(s) cannot overflow; p = z*m/(W + 1e-13*S) is
// algebraically identical to the max-shifted form. Halves LDS reads.
// ---------------------------------------------------------------------------
__global__ __launch_bounds__(512)
void attn_all(const float* __restrict__ combq, const float* __restrict__ combd,
              const float* __restrict__ qm, const float* __restrict__ dm,
              float* __restrict__ oq, float* __restrict__ od)
{
  __shared__ float4 s_kv[512];  // (k0*m, k1*m, v0, v1)
  __shared__ float  s_m[512];
  const int bid = blockIdx.x;
  const bool doc = (bid < 512);
  const int bh = doc ? bid : bid - 512;
  const int b = bh >> 5, h = bh & 31;
  const int T = doc ? TD_ : TQ_;
  const float* comb = doc ? combd : combq;
  const float* mask = doc ? dm : qm;
  float* o = doc ? od : oq;
  const int tid = threadIdx.x;
  const float* cb = comb + (size_t)b * T * CD_;
  if (tid < T) {
    const float* c = cb + (size_t)tid * CD_;
    const float m = mask[b * T + tid];
    s_kv[tid] = make_float4(c[AD_ + 2 * h] * m, c[AD_ + 2 * h + 1] * m,
                            c[2 * AD_ + 2 * h], c[2 * AD_ + 2 * h + 1]);
    s_m[tid] = m;
  }
  __syncthreads();
  if (tid < T) {
    const float* c = cb + (size_t)tid * CD_;
    const float q0 = c[2 * h] * (1.f / 3.f);      // scale = sqrt(300//32) = 3
    const float q1 = c[2 * h + 1] * (1.f / 3.f);
    float S = 0.f, W = 0.f, a0 = 0.f, a1 = 0.f;
#pragma unroll 4
    for (int j = 0; j < T; ++j) {
      const float4 kv = s_kv[j];
      const float s = fmaf(q0, kv.x, q1 * kv.y);
      const float z = __expf(s);
      const float w = z * s_m[j];
      S += z; W += w;
      a0 = fmaf(w, kv.z, a0);
      a1 = fmaf(w, kv.w, a1);
    }
    const float dn = 1.f / (W + 1e-13f * S);
    float* op = o + (size_t)(b * T + tid) * AD_ + 2 * h;
    op[0] = a0 * dn;
    op[1] = a1 * dn;
  }
}

// ---------------------------------------------------------------------------
// encode_back_v8: merged doc+query, 16 tokens/block, Wo chunked via single
// 19.2 KB LDS buffer + T14 register prefetch (4 chunks of 16 rows).
// ---------------------------------------------------------------------------
__global__ __launch_bounds__(256)
void encode_back_v8(const float* __restrict__ oq, const float* __restrict__ od,
                    const float* __restrict__ ffq, const float* __restrict__ ffd,
                    const float* __restrict__ Wo, const float* __restrict__ bo,
                    const float* __restrict__ lng, const float* __restrict__ lnb,
                    const float* __restrict__ qm, const float* __restrict__ dm,
                    float* __restrict__ qctx, float* __restrict__ dctxT)
{
  __shared__ float  s_O[1024];     // o transposed+swizzled [c][16]
  __shared__ float4 s_wb[1200];    // Wo chunk buffer (19.2 KB, single)

  const int tid = threadIdx.x;
  const int ct = tid & 31, tg = tid >> 5;
  const int t0 = tg * 2;
  const bool doc = (blockIdx.x < DOCBLK_);
  const int sb = doc ? blockIdx.x : (blockIdx.x - DOCBLK_);
  const size_t tok0 = (size_t)sb * 16;
  const float* op = doc ? od : oq;
  const float* ffp = doc ? ffd : ffq;
  const float* mp = doc ? dm : qm;
  const int bb_ = doc ? (int)(tok0 >> 9) : 0;
  const int tp0 = doc ? (int)(tok0 & 511) : 0;

  const float4* Wof4 = (const float4*)Wo;   // 64x300 -> 4800 f4, 4 chunks x 1200

  float4 r0, r1, r2, r3, r4;
#define LOADB(srcp) { const float4* _s = (srcp); \
    r0 = _s[tid]; r1 = _s[tid + 256]; r2 = _s[tid + 512]; r3 = _s[tid + 768]; \
    if (tid + 1024 < 1200) r4 = _s[tid + 1024]; }
#define COMMITB() { s_wb[tid] = r0; s_wb[tid + 256] = r1; s_wb[tid + 512] = r2; \
    s_wb[tid + 768] = r3; if (tid + 1024 < 1200) s_wb[tid + 1024] = r4; }

  LOADB(Wof4);

  { // load o (16x64) transposed into s_O
    const int t = tid >> 4, c0 = (tid & 15) * 4;
    const float4 v = *(const float4*)(op + (tok0 + t) * AD_ + c0);
    s_O[swz16(c0 + 0, t)] = v.x; s_O[swz16(c0 + 1, t)] = v.y;
    s_O[swz16(c0 + 2, t)] = v.z; s_O[swz16(c0 + 3, t)] = v.w;
  }
  __syncthreads();

  const int q2 = (ct < 11) ? ct + 64 : 74;
  const bool val2 = (ct < 11);
  float4 a[3][2];
#pragma unroll
  for (int p = 0; p < 3; ++p)
#pragma unroll
    for (int rr = 0; rr < 2; ++rr) a[p][rr] = make_float4(0.f, 0.f, 0.f, 0.f);
  for (int c = 0; c < 4; ++c) {
    COMMITB();
    __syncthreads();
    if (c < 3) LOADB(Wof4 + 1200 * (c + 1))
#pragma unroll 4
    for (int kk = 0; kk < 16; ++kk) {
      const float2 ov = *(const float2*)&s_O[swz16(c * 16 + kk, t0)];
      const float4 w0 = s_wb[kk * 75 + ct];
      const float4 w1 = s_wb[kk * 75 + ct + 32];
      const float4 w2 = s_wb[kk * 75 + q2];
      fma4(a[0][0], ov.x, w0); fma4(a[0][1], ov.y, w0);
      fma4(a[1][0], ov.x, w1); fma4(a[1][1], ov.y, w1);
      fma4(a[2][0], ov.x, w2); fma4(a[2][1], ov.y, w2);
    }
    if (c < 3) __syncthreads();
  }
  // residual + LN stats
  float sum[2] = {0.f, 0.f}, sq[2] = {0.f, 0.f};
#pragma unroll
  for (int p = 0; p < 3; ++p) {
    const int qq = (p == 0) ? ct : (p == 1) ? ct + 32 : q2;
    const bool ok = (p < 2) || val2;
    if (!ok) break;
    const float4 bb = *(const float4*)&bo[4 * qq];
#pragma unroll
    for (int rr = 0; rr < 2; ++rr) {
      const int t = t0 + rr;
      const float4 f4 = *(const float4*)(ffp + (tok0 + t) * E_ + 4 * qq);
      float4 v = a[p][rr];
      v.x += bb.x + f4.x; v.y += bb.y + f4.y;
      v.z += bb.z + f4.z; v.w += bb.w + f4.w;
      a[p][rr] = v;
      sum[rr] += v.x + v.y + v.z + v.w;
      sq[rr] = fmaf(v.x, v.x, fmaf(v.y, v.y, fmaf(v.z, v.z, fmaf(v.w, v.w, sq[rr]))));
    }
  }
#pragma unroll
  for (int m = 1; m <= 16; m <<= 1) {
#pragma unroll
    for (int rr = 0; rr < 2; ++rr) {
      sum[rr] += __shfl_xor(sum[rr], m);
      sq[rr]  += __shfl_xor(sq[rr], m);
    }
  }
#pragma unroll
  for (int rr = 0; rr < 2; ++rr) {
    const int t = t0 + rr;
    const float mean = sum[rr] * (1.f / 300.f);
    const float var  = fmaxf(sq[rr] * (1.f / 300.f) - mean * mean, 0.f);
    const float rstd = 1.f / (sqrtf(var) + 1e-6f);
    const float mk = mp[tok0 + t];
#pragma unroll
    for (int p = 0; p < 3; ++p) {
      if (p == 2 && !val2) break;
      const int qq = (p == 0) ? ct : (p == 1) ? ct + 32 : q2;
      const int c0 = 4 * qq;
      const float4 g4 = *(const float4*)&lng[c0];
      const float4 b4 = *(const float4*)&lnb[c0];
      const float4 v = a[p][rr];
      float4 fv;
      fv.x = fmaf(g4.x, (v.x - mean) * rstd, b4.x) * mk;
      fv.y = fmaf(g4.y, (v.y - mean) * rstd, b4.y) * mk;
      fv.z = fmaf(g4.z, (v.z - mean) * rstd, b4.z) * mk;
      fv.w = fmaf(g4.w, (v.w - mean) * rstd, b4.w) * mk;
      if (doc) {
        const int tp = tp0 + t;
        dctxT[((size_t)bb_ * E_ + c0 + 0) * 512 + tp] = fv.x;
        dctxT[((size_t)bb_ * E_ + c0 + 1) * 512 + tp] = fv.y;
        dctxT[((size_t)bb_ * E_ + c0 + 2) * 512 + tp] = fv.z;
        dctxT[((size_t)bb_ * E_ + c0 + 3) * 512 + tp] = fv.w;
      } else {
        *(float4*)&qctx[(tok0 + t) * E_ + c0] = fv;
      }
    }
  }
#undef LOADB
#undef COMMITB
}

// ---------------------------------------------------------------------------
// simtanh_v2: 256 blocks (b,qh,dc: 16x2x8) x 512 threads (epart=wave 0..7,
// dlane 0..63). Partial dots + LDS reduce, tanh, coalesced store.
// ---------------------------------------------------------------------------
__global__ __launch_bounds__(512)
void simtanh_v2(const float* __restrict__ qctx, const float* __restrict__ qn,
                const float* __restrict__ dctxT, const float* __restrict__ dnT,
                float* __restrict__ combined)
{
  __shared__ float s_q[2 * 16 * 304];     // [type][q][e]
  __shared__ float s_part[8 * 32 * 64];   // [epart][q*2+type][dlane]

  const int bid = blockIdx.x;
  const int sub = bid & 15, b = bid >> 4;
  const int qh = sub >> 3, dc = sub & 7;
  const int tid = threadIdx.x;
  const int ep = tid >> 6, dlane = tid & 63;
  const int d = dc * 64 + dlane;

  const float* qc  = qctx + ((size_t)b * 32 + qh * 16) * E_;
  const float* qnp = qn   + ((size_t)b * 32 + qh * 16) * E_;
  for (int i = tid; i < 1200; i += 512) {
    const int q = i / 75, e0 = (i % 75) * 4;
    *(float4*)&s_q[(0 * 16 + q) * 304 + e0] = *(const float4*)(qc + q * E_ + e0);
    *(float4*)&s_q[(1 * 16 + q) * 304 + e0] = *(const float4*)(qnp + q * E_ + e0);
  }
  __syncthreads();

  const float* dct = dctxT + (size_t)b * E_ * 512 + d;
  const float* dnt = dnT   + (size_t)b * E_ * 512 + d;
  float accD[16], accC[16];
#pragma unroll
  for (int q = 0; q < 16; ++q) { accD[q] = 0.f; accC[q] = 0.f; }
  const int es = ep * 40, ee = (es + 40 < 300) ? es + 40 : 300;
  for (int e0 = es; e0 < ee; e0 += 4) {
    const float dv0 = dct[(size_t)(e0 + 0) * 512];
    const float dv1 = dct[(size_t)(e0 + 1) * 512];
    const float dv2 = dct[(size_t)(e0 + 2) * 512];
    const float dv3 = dct[(size_t)(e0 + 3) * 512];
    const float dn0 = dnt[(size_t)(e0 + 0) * 512];
    const float dn1 = dnt[(size_t)(e0 + 1) * 512];
    const float dn2 = dnt[(size_t)(e0 + 2) * 512];
    const float dn3 = dnt[(size_t)(e0 + 3) * 512];
#pragma unroll
    for (int q = 0; q < 16; ++q) {
      const float4 qd = *(const float4*)&s_q[(0 * 16 + q) * 304 + e0];
      const float4 qc4 = *(const float4*)&s_q[(1 * 16 + q) * 304 + e0];
      float aD = accD[q], aC = accC[q];
      aD = fmaf(qd.x, dv0, aD); aD = fmaf(qd.y, dv1, aD);
      aD = fmaf(qd.z, dv2, aD); aD = fmaf(qd.w, dv3, aD);
      aC = fmaf(qc4.x, dn0, aC); aC = fmaf(qc4.y, dn1, aC);
      aC = fmaf(qc4.z, dn2, aC); aC = fmaf(qc4.w, dn3, aC);
      accD[q] = aD; accC[q] = aC;
    }
  }
#pragma unroll
  for (int q = 0; q < 16; ++q) {
    s_part[(ep * 32 + q * 2 + 0) * 64 + dlane] = accC[q];  // cos
    s_part[(ep * 32 + q * 2 + 1) * 64 + dlane] = accD[q];  // dot
  }
  __syncthreads();
  const int s0 = (tid >> 6) * 4;
#pragma unroll
  for (int si = 0; si < 4; ++si) {
    const int s = s0 + si;
    float v = 0.f;
#pragma unroll
    for (int p = 0; p < 8; ++p) v += s_part[(p * 32 + s) * 64 + dlane];
    const int q = s >> 1, typ = s & 1;
    combined[(((size_t)b * 2 + typ) * 32 + qh * 16 + q) * 512 + d] = tanhf(v);
  }
}

// ---------------------------------------------------------------------------
// conv_all: 5 convs (k=1..5, end-padded) + channel-max -> (B,5,32,512).
// Results stored immediately (keeps register pressure one-conv-wide; the
// fused variant spilled to scratch — 2.5 GB/dispatch HBM traffic, R6).
// ---------------------------------------------------------------------------
template <int K>
__device__ __forceinline__ float conv_max16(const float* __restrict__ s_in, int j,
                                            const float* __restrict__ w,
                                            const float* __restrict__ bias)
{
  float patch[2][K][K];
#pragma unroll
  for (int c = 0; c < 2; ++c)
#pragma unroll
    for (int di = 0; di < K; ++di)
#pragma unroll
      for (int dj = 0; dj < K; ++dj)
        patch[c][di][dj] = s_in[(c * 5 + di) * 516 + j + dj];
  float best = -1e30f;
#pragma unroll
  for (int oc = 0; oc < 16; ++oc) {
    float acc = bias[oc];
#pragma unroll
    for (int c = 0; c < 2; ++c)
#pragma unroll
      for (int di = 0; di < K; ++di)
#pragma unroll
        for (int dj = 0; dj < K; ++dj)
          acc = fmaf(patch[c][di][dj], w[((oc * 2 + c) * K + di) * K + dj], acc);
    best = fmaxf(best, acc);
  }
  return best;
}

__global__ __launch_bounds__(512)
void conv_all(const float* __restrict__ combined,
              const float* __restrict__ c1w, const float* __restrict__ c1b,
              const float* __restrict__ c2w, const float* __restrict__ c2b,
              const float* __restrict__ c3w, const float* __restrict__ c3b,
              const float* __restrict__ c4w, const float* __restrict__ c4b,
              const float* __restrict__ c5w, const float* __restrict__ c5b,
              float* __restrict__ convout)
{
  __shared__ float s_in[2 * 5 * 516];
  __shared__ float s_w[1730];
  __shared__ float s_b[66];
  const int blk = blockIdx.x, b = blk >> 5, i = blk & 31;
  const int tid = threadIdx.x;
  for (int idx = tid; idx < 2 * 5 * 516; idx += 512) {
    const int c = idx / (5 * 516), rem = idx % (5 * 516), r = rem / 516, j = rem % 516;
    const int row = i + r;
    float v = 0.f;
    if (row < 32 && j < 512)
      v = combined[((size_t)(b * 2 + c) * 32 + row) * 512 + j];
    s_in[idx] = v;
  }
  if (tid < 2)   s_w[tid] = c1w[tid];
  if (tid < 128) s_w[2 + tid] = c2w[tid];
  if (tid < 288) s_w[130 + tid] = c3w[tid];
  s_w[418 + tid] = c4w[tid];
  for (int idx = tid; idx < 800; idx += 512) s_w[930 + idx] = c5w[idx];
  if (tid == 0) s_b[0] = c1b[0];
  if (tid < 16) {
    s_b[1 + tid]  = c2b[tid];
    s_b[17 + tid] = c3b[tid];
    s_b[33 + tid] = c4b[tid];
    s_b[49 + tid] = c5b[tid];
  }
  __syncthreads();
  const int j = tid;
  const float o1 = fmaf(s_in[j], s_w[0], fmaf(s_in[5 * 516 + j], s_w[1], s_b[0]));
  convout[((size_t)(b * 5 + 0) * 32 + i) * 512 + j] = o1;
  convout[((size_t)(b * 5 + 1) * 32 + i) * 512 + j] = conv_max16<2>(s_in, j, s_w + 2,   s_b + 1);
  convout[((size_t)(b * 5 + 2) * 32 + i) * 512 + j] = conv_max16<3>(s_in, j, s_w + 130, s_b + 17);
  convout[((size_t)(b * 5 + 3) * 32 + i) * 512 + j] = conv_max16<4>(s_in, j, s_w + 418, s_b + 33);
  convout[((size_t)(b * 5 + 4) * 32 + i) * 512 + j] = conv_max16<5>(s_in, j, s_w + 930, s_b + 49);
}

// ---------------------------------------------------------------------------
// rbf_pkq
// ---------------------------------------------------------------------------
__global__ __launch_bounds__(512)
void rbf_pkq(const float* __restrict__ convout, const float* __restrict__ dmask,
             const float* __restrict__ qmask, float* __restrict__ pkq)
{
  __shared__ float red[8][NK_];
  const int id = blockIdx.x;
  const int q = id & 31;
  const int b = id / 160;
  const int tid = threadIdx.x;
  const float x = convout[(size_t)id * 512 + tid];
  const float dmv = dmask[b * 512 + tid];
  const float mu[NK_]  = {1.f, .9f, .7f, .5f, .3f, .1f, -.1f, -.3f, -.5f, -.7f, -.9f};
  const float nis[NK_] = {-5e7f, -50.f, -50.f, -50.f, -50.f, -50.f,
                          -50.f, -50.f, -50.f, -50.f, -50.f};
  const int lane = tid & 63, w = tid >> 6;
#pragma unroll
  for (int k = 0; k < NK_; ++k) {
    const float df = x - mu[k];
    float v = __expf(df * df * nis[k]) * dmv;
    v = wave_sum(v);
    if (lane == 0) red[w][k] = v;
  }
  __syncthreads();
  if (tid < NK_) {
    float s = 0.f;
#pragma unroll
    for (int ww = 0; ww < 8; ++ww) s += red[ww][tid];
    pkq[(size_t)id * NK_ + tid] = s * qmask[b * 32 + q];
  }
}

// ---------------------------------------------------------------------------
// final_k
// ---------------------------------------------------------------------------
__global__ __launch_bounds__(64)
void final_k(const float* __restrict__ pkq, const float* __restrict__ qmask,
             const float* __restrict__ dmask,
             const float* __restrict__ dw, const float* __restrict__ db,
             const float* __restrict__ dmw, const float* __restrict__ dmb,
             const float* __restrict__ cw, float* __restrict__ out)
{
  const int b = blockIdx.x, tid = threadIdx.x;
  float dl = 0.f;
  for (int j = tid; j < 512; j += 64) dl += dmask[b * 512 + j];
  dl = wave_sum(dl);
  dl = __shfl(dl, 0);
  float v1 = 0.f, v2 = 0.f;
  if (tid < 55) {
    const int c = tid / NK_, k = tid % NK_;
    const float rdl = 1.f / dl;
    float s1 = 0.f, s2 = 0.f;
    for (int q = 0; q < 32; ++q) {
      const float p = pkq[(size_t)((b * 5 + c) * 32 + q) * NK_ + k];
      const float qmv = qmask[b * 32 + q];
      s1 += logf(fmaxf(p, 1e-10f)) * qmv;
      s2 += logf(fmaxf(p * rdl, 1e-10f)) * qmv;
    }
    v1 = s1 * dw[tid];
    v2 = s2 * dmw[tid];
  }
  v1 = wave_sum(v1);
  v2 = wave_sum(v2);
  if (tid == 0) out[b] = (v1 + db[0]) * cw[0] + (v2 + dmb[0]) * cw[1];
}

}  // namespace

extern "C" void kernel_launch(void* const* d_in, const int* in_sizes, int n_in,
                              void* d_out, int out_size, void* d_ws, size_t ws_size,
                              hipStream_t stream)
{
  const float* qe  = (const float*)d_in[0];
  const float* de  = (const float*)d_in[1];
  const float* qm  = (const float*)d_in[2];
  const float* dm  = (const float*)d_in[3];
  const float* W1  = (const float*)d_in[6];
  const float* b1  = (const float*)d_in[7];
  const float* W2  = (const float*)d_in[8];
  const float* b2  = (const float*)d_in[9];
  const float* ffg = (const float*)d_in[10];
  const float* ffb = (const float*)d_in[11];
  const float* Wc  = (const float*)d_in[12];
  const float* bc  = (const float*)d_in[13];
  const float* Wo  = (const float*)d_in[14];
  const float* bo  = (const float*)d_in[15];
  const float* lng = (const float*)d_in[16];
  const float* lnb = (const float*)d_in[17];
  const float* c1w = (const float*)d_in[18];
  const float* c1b = (const float*)d_in[19];
  const float* c2w = (const float*)d_in[20];
  const float* c2b = (const float*)d_in[21];
  const float* c3w = (const float*)d_in[22];
  const float* c3b = (const float*)d_in[23];
  const float* c4w = (const float*)d_in[24];
  const float* c4b = (const float*)d_in[25];
  const float* c5w = (const float*)d_in[26];
  const float* c5b = (const float*)d_in[27];
  const float* dwp  = (const float*)d_in[28];
  const float* dbp  = (const float*)d_in[29];
  const float* dmwp = (const float*)d_in[30];
  const float* dmbp = (const float*)d_in[31];
  const float* cwp  = (const float*)d_in[32];

  float* ws = (float*)d_ws;
  size_t off = 0;
  auto alloc = [&](size_t n) { float* p = ws + off; off += n; return p; };
  float* ffq      = alloc((size_t)B_ * TQ_ * E_);
  float* combq    = alloc((size_t)B_ * TQ_ * CD_);
  float* oq       = alloc((size_t)B_ * TQ_ * AD_);
  float* qctx     = alloc((size_t)B_ * TQ_ * E_);
  float* qn       = alloc((size_t)B_ * TQ_ * E_);
  float* ffd      = alloc((size_t)B_ * TD_ * E_);
  float* combd    = alloc((size_t)B_ * TD_ * CD_);
  float* od       = alloc((size_t)B_ * TD_ * AD_);
  float* dctxT    = alloc((size_t)B_ * E_ * TD_);
  float* dnT      = alloc((size_t)B_ * E_ * TD_);
  float* combined = alloc((size_t)B_ * 2 * TQ_ * TD_);
  float* convout  = alloc((size_t)B_ * 5 * TQ_ * TD_);
  float* pkq      = alloc((size_t)B_ * 5 * TQ_ * NK_);

  encode_front_v8<<<DOCBLK_ + 32, 256, 0, stream>>>(
      qe, de, W1, b1, W2, b2, ffg, ffb, Wc, bc,
      ffq, combq, qn, ffd, combd, dnT);
  attn_all<<<1024, 512, 0, stream>>>(combq, combd, qm, dm, oq, od);
  encode_back_v8<<<DOCBLK_ + 32, 256, 0, stream>>>(
      oq, od, ffq, ffd, Wo, bo, lng, lnb, qm, dm, qctx, dctxT);
  simtanh_v2<<<256, 512, 0, stream>>>(qctx, qn, dctxT, dnT, combined);
  conv_all<<<B_ * 32, 512, 0, stream>>>(
      combined, c1w, c1b, c2w, c2b, c3w, c3b, c4w, c4b, c5w, c5b, convout);
  rbf_pkq<<<B_ * 5 * TQ_, 512, 0, stream>>>(convout, dm, qm, pkq);
  final_k<<<B_, 64, 0, stream>>>(pkq, qm, dm, dwp, dbp, dmwp, dmbp, cwp,
                                 (float*)d_out);
}